// Round 1
// baseline (1845.878 us; speedup 1.0000x reference)
//
#include <hip/hip_runtime.h>

// ChebConv GNN: 3x ChebConv(K=5) + ReLU, global mean pool, linear head.
// N=50000, E=800000, F_IN=H1=64, H2=128, G=64, C=2.
// Strategy: CSR-by-dst built per call (no fp scatter atomics in props);
// prop = wave-per-node gather (lane=channel); fp32 register-tiled GEMMs.

constexpr int F = 64;    // F_IN = H1
constexpr int H2C = 128;
constexpr int GG = 64;   // graphs
constexpr int CC = 2;    // classes

// ---------------- edge preprocessing ----------------

__global__ void deg_hist(const int* __restrict__ ei, const float* __restrict__ attr,
                         float* __restrict__ deg, int E) {
  int e = blockIdx.x * 256 + threadIdx.x;
  if (e < E) atomicAdd(&deg[ei[e]], attr[e]);
}

__global__ void dis_k(float* __restrict__ deg, int n) {
  int i = blockIdx.x * 256 + threadIdx.x;
  if (i < n) { float d = deg[i]; deg[i] = d > 0.f ? rsqrtf(d) : 0.f; }
}

__global__ void norm_hist(const int* __restrict__ ei, const float* __restrict__ attr,
                          const float* __restrict__ dis, float* __restrict__ nrm,
                          int* __restrict__ cnt, int E) {
  int e = blockIdx.x * 256 + threadIdx.x;
  if (e < E) {
    int s = ei[e], d = ei[E + e];
    nrm[e] = -dis[s] * attr[e] * dis[d];
    atomicAdd(&cnt[d], 1);
  }
}

__global__ __launch_bounds__(1024) void scan_k(const int* __restrict__ cnt,
                                               int* __restrict__ off, int n) {
  __shared__ int wsum[16];
  __shared__ int wscan[16];
  __shared__ int sbase;
  int t = threadIdx.x;
  int lane = t & 63, w = t >> 6;
  if (t == 0) { sbase = 0; off[0] = 0; }
  __syncthreads();
  for (int start = 0; start < n; start += 1024) {
    int i = start + t;
    int v = (i < n) ? cnt[i] : 0;
    int x = v;
#pragma unroll
    for (int d = 1; d < 64; d <<= 1) {
      int y = __shfl_up(x, d, 64);
      if (lane >= d) x += y;
    }
    if (lane == 63) wsum[w] = x;
    __syncthreads();
    if (t < 64) {
      int s = (t < 16) ? wsum[t] : 0;
#pragma unroll
      for (int d = 1; d < 16; d <<= 1) {
        int y = __shfl_up(s, d, 64);
        if (lane >= d) s += y;
      }
      if (t < 16) wscan[t] = s;
    }
    __syncthreads();
    int wexcl = (w > 0) ? wscan[w - 1] : 0;
    int incl = x + wexcl + sbase;
    if (i < n) off[i + 1] = incl;
    int tot = wscan[15];
    __syncthreads();
    if (t == 0) sbase += tot;
    __syncthreads();
  }
}

__global__ void scatter_k(const int* __restrict__ ei, const float* __restrict__ nrm,
                          int* __restrict__ cur, int* __restrict__ srcS,
                          float* __restrict__ normS, int E) {
  int e = blockIdx.x * 256 + threadIdx.x;
  if (e < E) {
    int d = ei[E + e];
    int p = atomicAdd(&cur[d], 1);
    srcS[p] = ei[e];
    normS[p] = nrm[e];
  }
}

// ---------------- sparse propagation: wave per node, lane = channel ----------------
// out[n][lane] = a*sum_{e in CSR[n]} normS[e]*z[srcS[e]][lane]  (a=1 if !Tprev, else 2*acc - Tprev)

__global__ __launch_bounds__(256) void prop_k(const float* __restrict__ z,
                                              const int* __restrict__ off,
                                              const int* __restrict__ srcS,
                                              const float* __restrict__ normS,
                                              const float* __restrict__ Tprev,
                                              float* __restrict__ outp, int n) {
  int wid = (blockIdx.x * 256 + threadIdx.x) >> 6;
  int lane = threadIdx.x & 63;
  if (wid >= n) return;
  int s = off[wid], e = off[wid + 1];
  float acc = 0.f;
  for (int i = s; i < e; ++i) {
    acc = fmaf(normS[i], z[(size_t)srcS[i] * F + lane], acc);
  }
  float r;
  if (Tprev) r = 2.f * acc - Tprev[(size_t)wid * F + lane];
  else r = acc;
  outp[(size_t)wid * F + lane] = r;
}

// ---------------- dense: Y[n, H] (+)= X[n, 64] @ W[64, H] ----------------

template <int H>
__global__ __launch_bounds__(256) void gemm_k(const float* __restrict__ X,
                                              const float* __restrict__ W,
                                              float* __restrict__ Y, int n, int beta) {
  constexpr int BM = 4096 / H;  // 64 (H=64) or 32 (H=128)
  __shared__ float xs[BM][F + 1];
  __shared__ float ws[F][H];
  int tid = threadIdx.x;
  int base = blockIdx.x * BM;
  float* wsf = &ws[0][0];
  for (int i = tid; i < F * H; i += 256) wsf[i] = W[i];
  for (int i = tid; i < BM * F; i += 256) {
    int r = i >> 6, c = i & 63;
    int gr = base + r;
    xs[r][c] = (gr < n) ? X[(size_t)gr * F + c] : 0.f;
  }
  __syncthreads();
  constexpr int CT = H / 4;  // col-thread count: 16 or 32
  int ct = tid % CT, rt = tid / CT;
  int h0 = ct * 4, r0 = rt * 4;
  float acc[4][4];
#pragma unroll
  for (int i = 0; i < 4; ++i)
#pragma unroll
    for (int j = 0; j < 4; ++j) acc[i][j] = 0.f;
#pragma unroll 4
  for (int c = 0; c < F; ++c) {
    float4 wv = *(const float4*)&ws[c][h0];
    float xv[4];
#pragma unroll
    for (int i = 0; i < 4; ++i) xv[i] = xs[r0 + i][c];
#pragma unroll
    for (int i = 0; i < 4; ++i) {
      acc[i][0] = fmaf(xv[i], wv.x, acc[i][0]);
      acc[i][1] = fmaf(xv[i], wv.y, acc[i][1]);
      acc[i][2] = fmaf(xv[i], wv.z, acc[i][2]);
      acc[i][3] = fmaf(xv[i], wv.w, acc[i][3]);
    }
  }
#pragma unroll
  for (int i = 0; i < 4; ++i) {
    int gr = base + r0 + i;
    if (gr < n) {
      float4* yp = (float4*)&Y[(size_t)gr * H + h0];
      float4 v = make_float4(acc[i][0], acc[i][1], acc[i][2], acc[i][3]);
      if (beta) {
        float4 o = *yp;
        v.x += o.x; v.y += o.y; v.z += o.z; v.w += o.w;
      }
      *yp = v;
    }
  }
}

template <int H>
__global__ void bias_relu(float* __restrict__ Y, const float* __restrict__ b, int n) {
  int i = blockIdx.x * 256 + threadIdx.x;
  if (i < n * H) {
    float v = Y[i] + b[i & (H - 1)];
    Y[i] = v > 0.f ? v : 0.f;
  }
}

// ---------------- pooling + head ----------------

__global__ void pool_k(const float* __restrict__ h, const int* __restrict__ batch,
                       float* __restrict__ pool, float* __restrict__ cntf, int n) {
  int i = blockIdx.x * 256 + threadIdx.x;
  if (i >= n * H2C) return;
  int nn = i >> 7, c = i & (H2C - 1);
  int g = batch[nn];
  atomicAdd(&pool[g * H2C + c], h[i]);
  if (c == 0) atomicAdd(&cntf[g], 1.f);
}

__global__ void final_k(const float* __restrict__ pool, const float* __restrict__ cntf,
                        const float* __restrict__ Wl, const float* __restrict__ bl,
                        float* __restrict__ outp) {
  __shared__ float hgs[GG * H2C];
  int t = threadIdx.x;
  for (int i = t; i < GG * H2C; i += 256) {
    int g = i >> 7;
    float v = pool[i] / fmaxf(cntf[g], 1.f);
    hgs[i] = v;
    outp[GG * CC + i] = v;  // hg output
  }
  __syncthreads();
  for (int i = t; i < GG * CC; i += 256) {
    int g = i / CC, c = i % CC;
    float s = bl[c];
    for (int hh = 0; hh < H2C; ++hh) s += hgs[g * H2C + hh] * Wl[hh * CC + c];
    outp[i] = s;  // logits
  }
}

// ---------------- driver ----------------

extern "C" void kernel_launch(void* const* d_in, const int* in_sizes, int n_in,
                              void* d_out, int out_size, void* d_ws, size_t ws_size,
                              hipStream_t stream) {
  const float* x    = (const float*)d_in[0];
  const int*   ei   = (const int*)d_in[1];
  const float* attr = (const float*)d_in[2];
  const int*   batch= (const int*)d_in[3];
  const float* W1 = (const float*)d_in[4];
  const float* b1 = (const float*)d_in[5];
  const float* W2 = (const float*)d_in[6];
  const float* b2 = (const float*)d_in[7];
  const float* W3 = (const float*)d_in[8];
  const float* b3 = (const float*)d_in[9];
  const float* Wl = (const float*)d_in[10];
  const float* bl = (const float*)d_in[11];
  float* outp = (float*)d_out;

  const int N = in_sizes[3];
  const int E = in_sizes[2];
  const int K = in_sizes[4] / (F * F);  // 5

  char* p = (char*)d_ws;
  auto alloc = [&](size_t bytes) {
    char* r = p;
    p += (bytes + 255) & ~(size_t)255;
    return r;
  };
  float* deg   = (float*)alloc((size_t)N * 4);
  float* nrm   = (float*)alloc((size_t)E * 4);
  int*   cnt   = (int*)alloc((size_t)N * 4);
  int*   off   = (int*)alloc((size_t)(N + 1) * 4);
  int*   cur   = (int*)alloc((size_t)N * 4);
  int*   srcS  = (int*)alloc((size_t)E * 4);
  float* normS = (float*)alloc((size_t)E * 4);
  float* A  = (float*)alloc((size_t)N * F * 4);
  float* B  = (float*)alloc((size_t)N * F * 4);
  float* Cb = (float*)alloc((size_t)N * F * 4);
  float* Y1 = (float*)alloc((size_t)N * F * 4);
  float* Y2 = (float*)alloc((size_t)N * F * 4);
  float* Y3 = (float*)alloc((size_t)N * H2C * 4);
  float* pool = (float*)alloc((size_t)GG * H2C * 4);
  float* cntf = (float*)alloc((size_t)GG * 4);

  hipMemsetAsync(deg, 0, (size_t)N * 4, stream);
  hipMemsetAsync(cnt, 0, (size_t)N * 4, stream);
  hipMemsetAsync(pool, 0, (size_t)GG * H2C * 4, stream);
  hipMemsetAsync(cntf, 0, (size_t)GG * 4, stream);

  int eb = (E + 255) / 256;
  int nb = (N + 255) / 256;
  deg_hist<<<eb, 256, 0, stream>>>(ei, attr, deg, E);
  dis_k<<<nb, 256, 0, stream>>>(deg, N);
  norm_hist<<<eb, 256, 0, stream>>>(ei, attr, deg, nrm, cnt, E);
  scan_k<<<1, 1024, 0, stream>>>(cnt, off, N);
  hipMemcpyAsync(cur, off, (size_t)N * 4, hipMemcpyDeviceToDevice, stream);
  scatter_k<<<eb, 256, 0, stream>>>(ei, nrm, cur, srcS, normS, E);

  auto gemm = [&](const float* Xin, const float* Wslice, float* Yout, int Hout, int beta) {
    if (Hout == 64)
      gemm_k<64><<<(N + 63) / 64, 256, 0, stream>>>(Xin, Wslice, Yout, N, beta);
    else
      gemm_k<128><<<(N + 31) / 32, 256, 0, stream>>>(Xin, Wslice, Yout, N, beta);
  };
  auto prop = [&](const float* z, const float* Tprev, float* po) {
    prop_k<<<(N + 3) / 4, 256, 0, stream>>>(z, off, srcS, normS, Tprev, po, N);
  };

  auto run_layer = [&](const float* Xin, const float* Wk, const float* bk,
                       float* Yout, int Hout) {
    size_t ks = (size_t)F * Hout;
    gemm(Xin, Wk, Yout, Hout, 0);
    if (K > 1) {
      prop(Xin, nullptr, A);  // Tx1 = L_hat x
      gemm(A, Wk + ks, Yout, Hout, 1);
      const float* Tprev = Xin;
      float* Tcur = A;
      float* Tnext = B;
      float* spare = Cb;
      for (int k = 2; k < K; ++k) {
        prop(Tcur, Tprev, Tnext);  // Tnext = 2*L_hat*Tcur - Tprev
        gemm(Tnext, Wk + (size_t)k * ks, Yout, Hout, 1);
        const float* np = Tcur;
        float* ncur = Tnext;
        float* nnext = (k == 2) ? spare : (float*)Tprev;
        Tprev = np; Tcur = ncur; Tnext = nnext;
      }
    }
    if (Hout == 64)
      bias_relu<64><<<((size_t)N * 64 + 255) / 256, 256, 0, stream>>>(Yout, bk, N);
    else
      bias_relu<128><<<((size_t)N * 128 + 255) / 256, 256, 0, stream>>>(Yout, bk, N);
  };

  run_layer(x, W1, b1, Y1, 64);
  run_layer(Y1, W2, b2, Y2, 64);
  run_layer(Y2, W3, b3, Y3, 128);

  pool_k<<<((size_t)N * H2C + 255) / 256, 256, 0, stream>>>(Y3, batch, pool, cntf, N);
  final_k<<<1, 256, 0, stream>>>(pool, cntf, Wl, bl, outp);
}

// Round 2
// 913.400 us; speedup vs baseline: 2.0209x; 2.0209x over previous
//
#include <hip/hip_runtime.h>

// ChebConv GNN: 3x ChebConv(K=5) + ReLU, global mean pool, linear head.
// N=50000, E=800000, F_IN=H1=64, H2=128, G=64, C=2.
// R2: atomic-free pool+head (batch is sorted), packed-edge unrolled prop,
//     fused-K gemm (one gemm per layer, bias+relu epilogue), hierarchical scan.

constexpr int F = 64;    // F_IN = H1
constexpr int H2C = 128;
constexpr int GG = 64;   // graphs
constexpr int CC = 2;    // classes

// ---------------- edge preprocessing ----------------

// deg[src] += attr ; cnt[dst] += 1
__global__ void pre_hist(const int* __restrict__ ei, const float* __restrict__ attr,
                         float* __restrict__ deg, int* __restrict__ cnt, int E) {
  int e = blockIdx.x * 256 + threadIdx.x;
  if (e < E) {
    atomicAdd(&deg[ei[e]], attr[e]);
    atomicAdd(&cnt[ei[E + e]], 1);
  }
}

__global__ void dis_k(float* __restrict__ deg, int n) {
  int i = blockIdx.x * 256 + threadIdx.x;
  if (i < n) { float d = deg[i]; deg[i] = d > 0.f ? rsqrtf(d) : 0.f; }
}

__global__ void norm_k(const int* __restrict__ ei, const float* __restrict__ attr,
                       const float* __restrict__ dis, float* __restrict__ nrm, int E) {
  int e = blockIdx.x * 256 + threadIdx.x;
  if (e < E) {
    int s = ei[e], d = ei[E + e];
    nrm[e] = -dis[s] * attr[e] * dis[d];
  }
}

// ---- hierarchical scan: off[i+1] = inclusive sum of cnt[0..i], off[0]=0 ----

__global__ __launch_bounds__(256) void scan_a(const int* __restrict__ cnt,
                                              int* __restrict__ bsum, int n) {
  int t = threadIdx.x, lane = t & 63, w = t >> 6;
  int base = blockIdx.x * 1024 + t * 4;
  int s = 0;
#pragma unroll
  for (int j = 0; j < 4; ++j) { int i = base + j; if (i < n) s += cnt[i]; }
#pragma unroll
  for (int d = 1; d < 64; d <<= 1) s += __shfl_down(s, d, 64);
  __shared__ int ws[4];
  if (lane == 0) ws[w] = s;
  __syncthreads();
  if (t == 0) bsum[blockIdx.x] = ws[0] + ws[1] + ws[2] + ws[3];
}

__global__ void scan_b(int* __restrict__ bsum, int nb) {
  if (threadIdx.x == 0) {
    int acc = 0;
    for (int i = 0; i < nb; ++i) { acc += bsum[i]; bsum[i] = acc; }
  }
}

__global__ __launch_bounds__(256) void scan_c(const int* __restrict__ cnt,
                                              const int* __restrict__ bscan,
                                              int* __restrict__ off, int n) {
  int b = blockIdx.x, t = threadIdx.x;
  int lane = t & 63, w = t >> 6;
  int idx = b * 1024 + t * 4;
  int v[4];
#pragma unroll
  for (int j = 0; j < 4; ++j) { int i = idx + j; v[j] = (i < n) ? cnt[i] : 0; }
  int s1 = v[0], s2 = s1 + v[1], s3 = s2 + v[2], s4 = s3 + v[3];
  int x = s4;
#pragma unroll
  for (int d = 1; d < 64; d <<= 1) { int y = __shfl_up(x, d, 64); if (lane >= d) x += y; }
  __shared__ int wtot[4];
  if (lane == 63) wtot[w] = x;
  __syncthreads();
  int wbase = 0;
  for (int i = 0; i < w; ++i) wbase += wtot[i];
  int base = ((b > 0) ? bscan[b - 1] : 0) + wbase + (x - s4);
  if (idx + 0 < n) off[idx + 1] = base + s1;
  if (idx + 1 < n) off[idx + 2] = base + s2;
  if (idx + 2 < n) off[idx + 3] = base + s3;
  if (idx + 3 < n) off[idx + 4] = base + s4;
  if (b == 0 && t == 0) off[0] = 0;
}

// scatter into CSR-by-dst, packed (src, norm-bits) per edge
__global__ void scatter_k(const int* __restrict__ ei, const float* __restrict__ nrm,
                          int* __restrict__ cur, int2* __restrict__ ep, int E) {
  int e = blockIdx.x * 256 + threadIdx.x;
  if (e < E) {
    int d = ei[E + e];
    int p = atomicAdd(&cur[d], 1);
    ep[p] = make_int2(ei[e], __float_as_int(nrm[e]));
  }
}

// ---------------- sparse propagation: wave per node, lane = channel ----------------
// out[n][lane] = a (a=1 if !Tprev) where acc=sum_{e in CSR[n]} w_e*z[src_e][lane];
// r = Tprev ? 2*acc - Tprev[n][lane] : acc

__global__ __launch_bounds__(256) void prop_k(const float* __restrict__ z,
                                              const int* __restrict__ off,
                                              const int2* __restrict__ ep,
                                              const float* __restrict__ Tprev,
                                              float* __restrict__ outp, int n) {
  int wid = (blockIdx.x * 256 + threadIdx.x) >> 6;
  int lane = threadIdx.x & 63;
  if (wid >= n) return;
  int s = off[wid], e = off[wid + 1];
  float a0 = 0.f, a1 = 0.f, a2 = 0.f, a3 = 0.f;
  int i = s;
  for (; i + 4 <= e; i += 4) {
    int2 m0 = ep[i], m1 = ep[i + 1], m2 = ep[i + 2], m3 = ep[i + 3];
    float z0 = z[(size_t)m0.x * F + lane];
    float z1 = z[(size_t)m1.x * F + lane];
    float z2 = z[(size_t)m2.x * F + lane];
    float z3 = z[(size_t)m3.x * F + lane];
    a0 = fmaf(__int_as_float(m0.y), z0, a0);
    a1 = fmaf(__int_as_float(m1.y), z1, a1);
    a2 = fmaf(__int_as_float(m2.y), z2, a2);
    a3 = fmaf(__int_as_float(m3.y), z3, a3);
  }
  for (; i < e; ++i) {
    int2 m = ep[i];
    a0 = fmaf(__int_as_float(m.y), z[(size_t)m.x * F + lane], a0);
  }
  float acc = (a0 + a1) + (a2 + a3);
  float r;
  if (Tprev) r = 2.f * acc - Tprev[(size_t)wid * F + lane];
  else r = acc;
  outp[(size_t)wid * F + lane] = r;
}

// ------- dense fused-K: Y[n,H] = relu( sum_k Tk[n,64] @ W[k,64,H] + b ) -------

template <int H>
__global__ __launch_bounds__(256) void gemm5_k(const float* __restrict__ T0,
                                               const float* __restrict__ T1,
                                               const float* __restrict__ T2,
                                               const float* __restrict__ T3,
                                               const float* __restrict__ T4,
                                               const float* __restrict__ W,
                                               const float* __restrict__ bias,
                                               float* __restrict__ Y, int n) {
  constexpr int BM = 4096 / H;  // 64 (H=64) or 32 (H=128)
  __shared__ float xs[BM][F + 1];
  __shared__ float ws[F][H];
  const float* Ts[5] = {T0, T1, T2, T3, T4};
  int tid = threadIdx.x;
  int base = blockIdx.x * BM;
  constexpr int CT = H / 4;
  int ct = tid % CT, rt = tid / CT;
  int h0 = ct * 4, r0 = rt * 4;
  float acc[4][4];
#pragma unroll
  for (int i = 0; i < 4; ++i)
#pragma unroll
    for (int j = 0; j < 4; ++j) acc[i][j] = 0.f;
  float* wsf = &ws[0][0];
#pragma unroll
  for (int k = 0; k < 5; ++k) {
    const float* X = Ts[k];
    const float* Wk = W + (size_t)k * F * H;
    for (int i = tid; i < F * H; i += 256) wsf[i] = Wk[i];
    for (int i = tid; i < BM * F; i += 256) {
      int r = i >> 6, c = i & 63;
      int gr = base + r;
      xs[r][c] = (gr < n) ? X[(size_t)gr * F + c] : 0.f;
    }
    __syncthreads();
#pragma unroll 4
    for (int c = 0; c < F; ++c) {
      float4 wv = *(const float4*)&ws[c][h0];
      float xv[4];
#pragma unroll
      for (int i = 0; i < 4; ++i) xv[i] = xs[r0 + i][c];
#pragma unroll
      for (int i = 0; i < 4; ++i) {
        acc[i][0] = fmaf(xv[i], wv.x, acc[i][0]);
        acc[i][1] = fmaf(xv[i], wv.y, acc[i][1]);
        acc[i][2] = fmaf(xv[i], wv.z, acc[i][2]);
        acc[i][3] = fmaf(xv[i], wv.w, acc[i][3]);
      }
    }
    __syncthreads();
  }
  float4 bv = *(const float4*)&bias[h0];
#pragma unroll
  for (int i = 0; i < 4; ++i) {
    int gr = base + r0 + i;
    if (gr < n) {
      float4 v = make_float4(fmaxf(acc[i][0] + bv.x, 0.f), fmaxf(acc[i][1] + bv.y, 0.f),
                             fmaxf(acc[i][2] + bv.z, 0.f), fmaxf(acc[i][3] + bv.w, 0.f));
      *(float4*)&Y[(size_t)gr * H + h0] = v;
    }
  }
}

// ---------------- pooling + head (batch is sorted: contiguous ranges) ----------------

__global__ void gbounds_k(const int* __restrict__ batch, int* __restrict__ gstart, int n) {
  int g = threadIdx.x;
  if (g > GG) return;
  int lo = 0, hi = n;
  while (lo < hi) {
    int mid = (lo + hi) >> 1;
    if (batch[mid] < g) lo = mid + 1; else hi = mid;
  }
  gstart[g] = lo;
}

__global__ __launch_bounds__(256) void pool_head_k(const float* __restrict__ h,
                                                   const int* __restrict__ gstart,
                                                   const float* __restrict__ Wl,
                                                   const float* __restrict__ bl,
                                                   float* __restrict__ outp) {
  int g = blockIdx.x;
  int s = gstart[g], e = gstart[g + 1];
  int tid = threadIdx.x;
  int c = tid & (H2C - 1);
  int half = tid >> 7;
  float acc = 0.f;
  for (int i = s + half; i < e; i += 2) acc += h[(size_t)i * H2C + c];
  __shared__ float sums[2][H2C];
  sums[half][c] = acc;
  __syncthreads();
  __shared__ float hgs[H2C];
  if (tid < H2C) {
    float cntv = fmaxf((float)(e - s), 1.f);
    float hg = (sums[0][tid] + sums[1][tid]) / cntv;
    outp[GG * CC + g * H2C + tid] = hg;
    hgs[tid] = hg;
  }
  __syncthreads();
  __shared__ float red[2][128];
  if (tid < 128) {
    float v = hgs[tid];
    red[0][tid] = v * Wl[tid * CC + 0];
    red[1][tid] = v * Wl[tid * CC + 1];
  }
  __syncthreads();
  for (int st = 64; st > 0; st >>= 1) {
    if (tid < st) { red[0][tid] += red[0][tid + st]; red[1][tid] += red[1][tid + st]; }
    __syncthreads();
  }
  if (tid == 0) {
    outp[g * CC + 0] = red[0][0] + bl[0];
    outp[g * CC + 1] = red[1][0] + bl[1];
  }
}

// ---------------- driver ----------------

extern "C" void kernel_launch(void* const* d_in, const int* in_sizes, int n_in,
                              void* d_out, int out_size, void* d_ws, size_t ws_size,
                              hipStream_t stream) {
  const float* x    = (const float*)d_in[0];
  const int*   ei   = (const int*)d_in[1];
  const float* attr = (const float*)d_in[2];
  const int*   batch= (const int*)d_in[3];
  const float* W1 = (const float*)d_in[4];
  const float* b1 = (const float*)d_in[5];
  const float* W2 = (const float*)d_in[6];
  const float* b2 = (const float*)d_in[7];
  const float* W3 = (const float*)d_in[8];
  const float* b3 = (const float*)d_in[9];
  const float* Wl = (const float*)d_in[10];
  const float* bl = (const float*)d_in[11];
  float* outp = (float*)d_out;

  const int N = in_sizes[3];
  const int E = in_sizes[2];

  char* p = (char*)d_ws;
  auto alloc = [&](size_t bytes) {
    char* r = p;
    p += (bytes + 255) & ~(size_t)255;
    return r;
  };
  float* deg   = (float*)alloc((size_t)N * 4);
  float* nrm   = (float*)alloc((size_t)E * 4);
  int*   cnt   = (int*)alloc((size_t)N * 4);
  int*   off   = (int*)alloc((size_t)(N + 1) * 4);
  int*   cur   = (int*)alloc((size_t)N * 4);
  int2*  ep    = (int2*)alloc((size_t)E * 8);
  int*   bsum  = (int*)alloc(4096);
  int*   gstart= (int*)alloc((size_t)(GG + 1) * 4);
  float* A  = (float*)alloc((size_t)N * F * 4);
  float* B  = (float*)alloc((size_t)N * F * 4);
  float* Cb = (float*)alloc((size_t)N * F * 4);
  float* Y1 = (float*)alloc((size_t)N * F * 4);
  float* Y2 = (float*)alloc((size_t)N * F * 4);
  float* Y3 = (float*)alloc((size_t)N * H2C * 4);

  hipMemsetAsync(deg, 0, (size_t)N * 4, stream);
  hipMemsetAsync(cnt, 0, (size_t)N * 4, stream);

  int eb = (E + 255) / 256;
  int nb = (N + 255) / 256;
  int sb = (N + 1023) / 1024;
  pre_hist<<<eb, 256, 0, stream>>>(ei, attr, deg, cnt, E);
  dis_k<<<nb, 256, 0, stream>>>(deg, N);
  norm_k<<<eb, 256, 0, stream>>>(ei, attr, deg, nrm, E);
  scan_a<<<sb, 256, 0, stream>>>(cnt, bsum, N);
  scan_b<<<1, 64, 0, stream>>>(bsum, sb);
  scan_c<<<sb, 256, 0, stream>>>(cnt, bsum, off, N);
  hipMemcpyAsync(cur, off, (size_t)N * 4, hipMemcpyDeviceToDevice, stream);
  scatter_k<<<eb, 256, 0, stream>>>(ei, nrm, cur, ep, E);
  gbounds_k<<<1, 128, 0, stream>>>(batch, gstart, N);

  auto prop = [&](const float* z, const float* Tprev, float* po) {
    prop_k<<<(N + 3) / 4, 256, 0, stream>>>(z, off, ep, Tprev, po, N);
  };

  auto run_layer = [&](const float* T0, float* T4, const float* Wk, const float* bk,
                       float* Yout, int Hout) {
    prop(T0, nullptr, A);   // T1
    prop(A, T0, B);         // T2
    prop(B, A, Cb);         // T3
    prop(Cb, B, T4);        // T4
    if (Hout == 64)
      gemm5_k<64><<<(N + 63) / 64, 256, 0, stream>>>(T0, A, B, Cb, T4, Wk, bk, Yout, N);
    else
      gemm5_k<128><<<(N + 31) / 32, 256, 0, stream>>>(T0, A, B, Cb, T4, Wk, bk, Yout, N);
  };

  run_layer(x,  Y2, W1, b1, Y1, 64);   // Y2 free -> T4 scratch
  run_layer(Y1, Y3, W2, b2, Y2, 64);   // Y3 free -> T4 scratch
  run_layer(Y2, Y1, W3, b3, Y3, 128);  // Y1 free -> T4 scratch

  pool_head_k<<<GG, 256, 0, stream>>>(Y3, gstart, Wl, bl, outp);
}

// Round 3
// 696.337 us; speedup vs baseline: 2.6508x; 1.3117x over previous
//
#include <hip/hip_runtime.h>

// ChebConv GNN: 3x ChebConv(K=5) + ReLU, global mean pool, linear head.
// N=50000, E=800000, F_IN=H1=64, H2=128, G=64, C=2.
// R3: bf16 MFMA fused-K gemm (no LDS, reg fragments), readlane-broadcast prop
//     with 8 outstanding gathers, norm fused into scatter.

constexpr int F = 64;    // F_IN = H1
constexpr int H2C = 128;
constexpr int GG = 64;   // graphs
constexpr int CC = 2;    // classes
constexpr int KT = 5;    // Chebyshev terms

typedef __attribute__((ext_vector_type(8))) short short8v;
typedef __attribute__((ext_vector_type(4))) float f32x4;

__device__ inline unsigned short f2bf(float f) {
  unsigned u = __float_as_uint(f);
  u = (u + 0x7fffu + ((u >> 16) & 1u)) >> 16;
  return (unsigned short)u;
}

// ---------------- edge preprocessing ----------------

// deg[src] += attr ; cnt[dst] += 1
__global__ void pre_hist(const int* __restrict__ ei, const float* __restrict__ attr,
                         float* __restrict__ deg, int* __restrict__ cnt, int E) {
  int e = blockIdx.x * 256 + threadIdx.x;
  if (e < E) {
    atomicAdd(&deg[ei[e]], attr[e]);
    atomicAdd(&cnt[ei[E + e]], 1);
  }
}

__global__ void dis_k(float* __restrict__ deg, int n) {
  int i = blockIdx.x * 256 + threadIdx.x;
  if (i < n) { float d = deg[i]; deg[i] = d > 0.f ? rsqrtf(d) : 0.f; }
}

// ---- hierarchical scan: off[i+1] = inclusive sum of cnt[0..i], off[0]=0 ----

__global__ __launch_bounds__(256) void scan_a(const int* __restrict__ cnt,
                                              int* __restrict__ bsum, int n) {
  int t = threadIdx.x, lane = t & 63, w = t >> 6;
  int base = blockIdx.x * 1024 + t * 4;
  int s = 0;
#pragma unroll
  for (int j = 0; j < 4; ++j) { int i = base + j; if (i < n) s += cnt[i]; }
#pragma unroll
  for (int d = 1; d < 64; d <<= 1) s += __shfl_down(s, d, 64);
  __shared__ int ws[4];
  if (lane == 0) ws[w] = s;
  __syncthreads();
  if (t == 0) bsum[blockIdx.x] = ws[0] + ws[1] + ws[2] + ws[3];
}

__global__ void scan_b(int* __restrict__ bsum, int nb) {
  if (threadIdx.x == 0) {
    int acc = 0;
    for (int i = 0; i < nb; ++i) { acc += bsum[i]; bsum[i] = acc; }
  }
}

__global__ __launch_bounds__(256) void scan_c(const int* __restrict__ cnt,
                                              const int* __restrict__ bscan,
                                              int* __restrict__ off, int n) {
  int b = blockIdx.x, t = threadIdx.x;
  int lane = t & 63, w = t >> 6;
  int idx = b * 1024 + t * 4;
  int v[4];
#pragma unroll
  for (int j = 0; j < 4; ++j) { int i = idx + j; v[j] = (i < n) ? cnt[i] : 0; }
  int s1 = v[0], s2 = s1 + v[1], s3 = s2 + v[2], s4 = s3 + v[3];
  int x = s4;
#pragma unroll
  for (int d = 1; d < 64; d <<= 1) { int y = __shfl_up(x, d, 64); if (lane >= d) x += y; }
  __shared__ int wtot[4];
  if (lane == 63) wtot[w] = x;
  __syncthreads();
  int wbase = 0;
  for (int i = 0; i < w; ++i) wbase += wtot[i];
  int base = ((b > 0) ? bscan[b - 1] : 0) + wbase + (x - s4);
  if (idx + 0 < n) off[idx + 1] = base + s1;
  if (idx + 1 < n) off[idx + 2] = base + s2;
  if (idx + 2 < n) off[idx + 3] = base + s3;
  if (idx + 3 < n) off[idx + 4] = base + s4;
  if (b == 0 && t == 0) off[0] = 0;
}

// scatter into CSR-by-dst, packed (src, norm-bits) per edge; norm computed inline
__global__ void scatter_k(const int* __restrict__ ei, const float* __restrict__ attr,
                          const float* __restrict__ dis, int* __restrict__ cur,
                          int2* __restrict__ ep, int E) {
  int e = blockIdx.x * 256 + threadIdx.x;
  if (e < E) {
    int s = ei[e], d = ei[E + e];
    float nrmv = -dis[s] * attr[e] * dis[d];
    int p = atomicAdd(&cur[d], 1);
    ep[p] = make_int2(s, __float_as_int(nrmv));
  }
}

// ---------------- sparse propagation: wave per node, lane = channel ----------------

__global__ __launch_bounds__(256) void prop_k(const float* __restrict__ z,
                                              const int* __restrict__ off,
                                              const int2* __restrict__ ep,
                                              const float* __restrict__ Tprev,
                                              float* __restrict__ outp, int n) {
  int wid = (blockIdx.x * 256 + threadIdx.x) >> 6;
  int lane = threadIdx.x & 63;
  if (wid >= n) return;
  int s = off[wid], e = off[wid + 1];
  float a0 = 0.f, a1 = 0.f, a2 = 0.f, a3 = 0.f;
  float a4 = 0.f, a5 = 0.f, a6 = 0.f, a7 = 0.f;
  for (int base = s; base < e; base += 64) {
    int idx = base + lane;
    int2 m = (idx < e) ? ep[idx] : make_int2(0, 0);  // coalesced bulk meta load
    int cnt = min(64, e - base);
    int j = 0;
    for (; j + 8 <= cnt; j += 8) {
#define RL(t) int s##t = __builtin_amdgcn_readlane(m.x, j + t); \
              float w##t = __int_as_float(__builtin_amdgcn_readlane(m.y, j + t));
      RL(0) RL(1) RL(2) RL(3) RL(4) RL(5) RL(6) RL(7)
#undef RL
      float z0 = z[(size_t)s0 * F + lane];
      float z1 = z[(size_t)s1 * F + lane];
      float z2 = z[(size_t)s2 * F + lane];
      float z3 = z[(size_t)s3 * F + lane];
      float z4 = z[(size_t)s4 * F + lane];
      float z5 = z[(size_t)s5 * F + lane];
      float z6 = z[(size_t)s6 * F + lane];
      float z7 = z[(size_t)s7 * F + lane];
      a0 = fmaf(w0, z0, a0); a1 = fmaf(w1, z1, a1);
      a2 = fmaf(w2, z2, a2); a3 = fmaf(w3, z3, a3);
      a4 = fmaf(w4, z4, a4); a5 = fmaf(w5, z5, a5);
      a6 = fmaf(w6, z6, a6); a7 = fmaf(w7, z7, a7);
    }
    for (; j < cnt; ++j) {
      int sj = __builtin_amdgcn_readlane(m.x, j);
      float wj = __int_as_float(__builtin_amdgcn_readlane(m.y, j));
      a0 = fmaf(wj, z[(size_t)sj * F + lane], a0);
    }
  }
  float acc = ((a0 + a1) + (a2 + a3)) + ((a4 + a5) + (a6 + a7));
  float r;
  if (Tprev) r = 2.f * acc - Tprev[(size_t)wid * F + lane];
  else r = acc;
  outp[(size_t)wid * F + lane] = r;
}

// ---------------- weight repack: fp32 W[term][k][n] -> bf16 B-fragments ----------------
// frag fid = (term*2 + ks)*CT + ct ; lane holds B[k][n] with
// n = ct*16 + (lane&15), k = ks*32 + (lane>>4)*8 + e   (e = 0..7)

__global__ void repack_k(const float* __restrict__ W, unsigned short* __restrict__ Bp,
                         int H) {
  int t = blockIdx.x * 256 + threadIdx.x;
  int lane = t & 63, fid = t >> 6;
  int CT = H / 16;
  int nf = KT * 2 * CT;
  if (fid >= nf) return;
  int ct = fid % CT;
  int ks = (fid / CT) & 1;
  int term = fid / (CT * 2);
  int nn = ct * 16 + (lane & 15);
  int kb = ks * 32 + (lane >> 4) * 8;
  unsigned short v[8];
#pragma unroll
  for (int e = 0; e < 8; ++e)
    v[e] = f2bf(W[((size_t)term * F + kb + e) * H + nn]);
  short8v* dst = (short8v*)Bp;
  short8v out;
#pragma unroll
  for (int e = 0; e < 8; ++e) out[e] = (short)v[e];
  dst[(size_t)fid * 64 + lane] = out;
}

// ------- MFMA fused-K: Y[n,H] = relu( sum_k Tk[n,64] @ W[k,64,H] + b ) -------
// block = 256 = 4 waves; each wave owns 16 rows x H cols. No LDS.

template <int H>
__global__ __launch_bounds__(256) void gemm5_mfma(const float* __restrict__ T0,
                                                  const float* __restrict__ T1,
                                                  const float* __restrict__ T2,
                                                  const float* __restrict__ T3,
                                                  const float* __restrict__ T4,
                                                  const unsigned short* __restrict__ Bp,
                                                  const float* __restrict__ bias,
                                                  float* __restrict__ Y, int n) {
  constexpr int CT = H / 16;
  int wave = threadIdx.x >> 6;
  int lane = threadIdx.x & 63;
  int rbase = blockIdx.x * 64 + wave * 16;
  int arow = rbase + (lane & 15);
  if (arow > n - 1) arow = n - 1;  // clamp loads; stores guarded
  const short8v* bp = (const short8v*)Bp;
  const float* Ts[5] = {T0, T1, T2, T3, T4};

  f32x4 acc[CT];
#pragma unroll
  for (int c = 0; c < CT; ++c) acc[c] = (f32x4){0.f, 0.f, 0.f, 0.f};

#pragma unroll
  for (int term = 0; term < KT; ++term) {
    const float* T = Ts[term];
#pragma unroll
    for (int ks = 0; ks < 2; ++ks) {
      int kb = ks * 32 + (lane >> 4) * 8;
      const float4* ap = (const float4*)(T + (size_t)arow * F + kb);
      float4 x0 = ap[0];
      float4 x1 = ap[1];
      short8v af;
      af[0] = (short)f2bf(x0.x); af[1] = (short)f2bf(x0.y);
      af[2] = (short)f2bf(x0.z); af[3] = (short)f2bf(x0.w);
      af[4] = (short)f2bf(x1.x); af[5] = (short)f2bf(x1.y);
      af[6] = (short)f2bf(x1.z); af[7] = (short)f2bf(x1.w);
      int fid0 = (term * 2 + ks) * CT;
#pragma unroll
      for (int ct = 0; ct < CT; ++ct) {
        short8v bf = bp[(size_t)(fid0 + ct) * 64 + lane];
        acc[ct] = __builtin_amdgcn_mfma_f32_16x16x32_bf16(af, bf, acc[ct], 0, 0, 0);
      }
    }
  }
  // C/D: col = lane&15, row = (lane>>4)*4 + reg
  int col0 = lane & 15;
  int rrow = rbase + (lane >> 4) * 4;
#pragma unroll
  for (int ct = 0; ct < CT; ++ct) {
    int col = ct * 16 + col0;
    float bv = bias[col];
#pragma unroll
    for (int i = 0; i < 4; ++i) {
      int gr = rrow + i;
      if (gr < n) Y[(size_t)gr * H + col] = fmaxf(acc[ct][i] + bv, 0.f);
    }
  }
}

// ---------------- pooling + head (batch is sorted: contiguous ranges) ----------------

__global__ void gbounds_k(const int* __restrict__ batch, int* __restrict__ gstart, int n) {
  int g = threadIdx.x;
  if (g > GG) return;
  int lo = 0, hi = n;
  while (lo < hi) {
    int mid = (lo + hi) >> 1;
    if (batch[mid] < g) lo = mid + 1; else hi = mid;
  }
  gstart[g] = lo;
}

__global__ __launch_bounds__(256) void pool_head_k(const float* __restrict__ h,
                                                   const int* __restrict__ gstart,
                                                   const float* __restrict__ Wl,
                                                   const float* __restrict__ bl,
                                                   float* __restrict__ outp) {
  int g = blockIdx.x;
  int s = gstart[g], e = gstart[g + 1];
  int tid = threadIdx.x;
  int c = tid & (H2C - 1);
  int half = tid >> 7;
  float acc = 0.f;
  for (int i = s + half; i < e; i += 2) acc += h[(size_t)i * H2C + c];
  __shared__ float sums[2][H2C];
  sums[half][c] = acc;
  __syncthreads();
  __shared__ float hgs[H2C];
  if (tid < H2C) {
    float cntv = fmaxf((float)(e - s), 1.f);
    float hg = (sums[0][tid] + sums[1][tid]) / cntv;
    outp[GG * CC + g * H2C + tid] = hg;
    hgs[tid] = hg;
  }
  __syncthreads();
  __shared__ float red[2][128];
  if (tid < 128) {
    float v = hgs[tid];
    red[0][tid] = v * Wl[tid * CC + 0];
    red[1][tid] = v * Wl[tid * CC + 1];
  }
  __syncthreads();
  for (int st = 64; st > 0; st >>= 1) {
    if (tid < st) { red[0][tid] += red[0][tid + st]; red[1][tid] += red[1][tid + st]; }
    __syncthreads();
  }
  if (tid == 0) {
    outp[g * CC + 0] = red[0][0] + bl[0];
    outp[g * CC + 1] = red[1][0] + bl[1];
  }
}

// ---------------- driver ----------------

extern "C" void kernel_launch(void* const* d_in, const int* in_sizes, int n_in,
                              void* d_out, int out_size, void* d_ws, size_t ws_size,
                              hipStream_t stream) {
  const float* x    = (const float*)d_in[0];
  const int*   ei   = (const int*)d_in[1];
  const float* attr = (const float*)d_in[2];
  const int*   batch= (const int*)d_in[3];
  const float* W1 = (const float*)d_in[4];
  const float* b1 = (const float*)d_in[5];
  const float* W2 = (const float*)d_in[6];
  const float* b2 = (const float*)d_in[7];
  const float* W3 = (const float*)d_in[8];
  const float* b3 = (const float*)d_in[9];
  const float* Wl = (const float*)d_in[10];
  const float* bl = (const float*)d_in[11];
  float* outp = (float*)d_out;

  const int N = in_sizes[3];
  const int E = in_sizes[2];

  char* p = (char*)d_ws;
  auto alloc = [&](size_t bytes) {
    char* r = p;
    p += (bytes + 255) & ~(size_t)255;
    return r;
  };
  float* deg   = (float*)alloc((size_t)N * 4);
  int*   cnt   = (int*)alloc((size_t)N * 4);
  int*   off   = (int*)alloc((size_t)(N + 1) * 4);
  int*   cur   = (int*)alloc((size_t)N * 4);
  int2*  ep    = (int2*)alloc((size_t)E * 8);
  int*   bsum  = (int*)alloc(4096);
  int*   gstart= (int*)alloc((size_t)(GG + 1) * 4);
  unsigned short* Bp1 = (unsigned short*)alloc((size_t)KT * 2 * 4 * 64 * 8 * 2);
  unsigned short* Bp2 = (unsigned short*)alloc((size_t)KT * 2 * 4 * 64 * 8 * 2);
  unsigned short* Bp3 = (unsigned short*)alloc((size_t)KT * 2 * 8 * 64 * 8 * 2);
  float* A  = (float*)alloc((size_t)N * F * 4);
  float* B  = (float*)alloc((size_t)N * F * 4);
  float* Cb = (float*)alloc((size_t)N * F * 4);
  float* Y1 = (float*)alloc((size_t)N * F * 4);
  float* Y2 = (float*)alloc((size_t)N * F * 4);
  float* Y3 = (float*)alloc((size_t)N * H2C * 4);

  hipMemsetAsync(deg, 0, (size_t)N * 4, stream);
  hipMemsetAsync(cnt, 0, (size_t)N * 4, stream);

  int eb = (E + 255) / 256;
  int nb = (N + 255) / 256;
  int sb = (N + 1023) / 1024;

  // weight repacks (independent of graph preprocessing)
  repack_k<<<(KT * 2 * 4 * 64 + 255) / 256, 256, 0, stream>>>(W1, Bp1, 64);
  repack_k<<<(KT * 2 * 4 * 64 + 255) / 256, 256, 0, stream>>>(W2, Bp2, 64);
  repack_k<<<(KT * 2 * 8 * 64 + 255) / 256, 256, 0, stream>>>(W3, Bp3, 128);

  pre_hist<<<eb, 256, 0, stream>>>(ei, attr, deg, cnt, E);
  dis_k<<<nb, 256, 0, stream>>>(deg, N);
  scan_a<<<sb, 256, 0, stream>>>(cnt, bsum, N);
  scan_b<<<1, 64, 0, stream>>>(bsum, sb);
  scan_c<<<sb, 256, 0, stream>>>(cnt, bsum, off, N);
  hipMemcpyAsync(cur, off, (size_t)N * 4, hipMemcpyDeviceToDevice, stream);
  scatter_k<<<eb, 256, 0, stream>>>(ei, attr, deg, cur, ep, E);
  gbounds_k<<<1, 128, 0, stream>>>(batch, gstart, N);

  auto prop = [&](const float* z, const float* Tprev, float* po) {
    prop_k<<<(N + 3) / 4, 256, 0, stream>>>(z, off, ep, Tprev, po, N);
  };

  auto run_layer = [&](const float* T0, float* T4, const unsigned short* Bpk,
                       const float* bk, float* Yout, int Hout) {
    prop(T0, nullptr, A);   // T1
    prop(A, T0, B);         // T2
    prop(B, A, Cb);         // T3
    prop(Cb, B, T4);        // T4
    if (Hout == 64)
      gemm5_mfma<64><<<(N + 63) / 64, 256, 0, stream>>>(T0, A, B, Cb, T4, Bpk, bk, Yout, N);
    else
      gemm5_mfma<128><<<(N + 63) / 64, 256, 0, stream>>>(T0, A, B, Cb, T4, Bpk, bk, Yout, N);
  };

  run_layer(x,  Y2, Bp1, b1, Y1, 64);   // Y2 free -> T4 scratch
  run_layer(Y1, Y3, Bp2, b2, Y2, 64);   // Y3 free -> T4 scratch
  run_layer(Y2, Y1, Bp3, b3, Y3, 128);  // Y1 free -> T4 scratch

  pool_head_k<<<GG, 256, 0, stream>>>(Y3, gstart, Wl, bl, outp);
}

// Round 4
// 544.865 us; speedup vs baseline: 3.3878x; 1.2780x over previous
//
#include <hip/hip_runtime.h>

// ChebConv GNN: 3x ChebConv(K=5) + ReLU, global mean pool, linear head.
// N=50000, E=800000, F_IN=H1=64, H2=128, G=64, C=2.
// R4: bf16 T-matrix storage (halves gather bytes; fp32 shadow only for T1/T2
//     used as Tprev), two-stage atomic-free pool, bf16 Y buffers throughout.

constexpr int F = 64;    // F_IN = H1
constexpr int H2C = 128;
constexpr int GG = 64;   // graphs
constexpr int CC = 2;    // classes
constexpr int KT = 5;    // Chebyshev terms
constexpr int PP = 16;   // pool partial blocks per graph

typedef __attribute__((ext_vector_type(8))) short short8v;
typedef __attribute__((ext_vector_type(4))) float f32x4;
typedef unsigned short ushortT;
typedef __attribute__((ext_vector_type(4))) unsigned short u16x4;

__device__ inline ushortT f2bf(float f) {
  unsigned u = __float_as_uint(f);
  u = (u + 0x7fffu + ((u >> 16) & 1u)) >> 16;
  return (ushortT)u;
}
__device__ inline float bf2f(ushortT u) {
  return __uint_as_float((unsigned)u << 16);
}

// ---------------- edge preprocessing ----------------

__global__ void pre_hist(const int* __restrict__ ei, const float* __restrict__ attr,
                         float* __restrict__ deg, int* __restrict__ cnt, int E) {
  int e = blockIdx.x * 256 + threadIdx.x;
  if (e < E) {
    atomicAdd(&deg[ei[e]], attr[e]);
    atomicAdd(&cnt[ei[E + e]], 1);
  }
}

__global__ void dis_k(float* __restrict__ deg, int n) {
  int i = blockIdx.x * 256 + threadIdx.x;
  if (i < n) { float d = deg[i]; deg[i] = d > 0.f ? rsqrtf(d) : 0.f; }
}

// ---- hierarchical scan: off[i+1] = inclusive sum of cnt[0..i], off[0]=0 ----

__global__ __launch_bounds__(256) void scan_a(const int* __restrict__ cnt,
                                              int* __restrict__ bsum, int n) {
  int t = threadIdx.x, lane = t & 63, w = t >> 6;
  int base = blockIdx.x * 1024 + t * 4;
  int s = 0;
#pragma unroll
  for (int j = 0; j < 4; ++j) { int i = base + j; if (i < n) s += cnt[i]; }
#pragma unroll
  for (int d = 1; d < 64; d <<= 1) s += __shfl_down(s, d, 64);
  __shared__ int ws[4];
  if (lane == 0) ws[w] = s;
  __syncthreads();
  if (t == 0) bsum[blockIdx.x] = ws[0] + ws[1] + ws[2] + ws[3];
}

__global__ void scan_b(int* __restrict__ bsum, int nb) {
  if (threadIdx.x == 0) {
    int acc = 0;
    for (int i = 0; i < nb; ++i) { acc += bsum[i]; bsum[i] = acc; }
  }
}

__global__ __launch_bounds__(256) void scan_c(const int* __restrict__ cnt,
                                              const int* __restrict__ bscan,
                                              int* __restrict__ off, int n) {
  int b = blockIdx.x, t = threadIdx.x;
  int lane = t & 63, w = t >> 6;
  int idx = b * 1024 + t * 4;
  int v[4];
#pragma unroll
  for (int j = 0; j < 4; ++j) { int i = idx + j; v[j] = (i < n) ? cnt[i] : 0; }
  int s1 = v[0], s2 = s1 + v[1], s3 = s2 + v[2], s4 = s3 + v[3];
  int x = s4;
#pragma unroll
  for (int d = 1; d < 64; d <<= 1) { int y = __shfl_up(x, d, 64); if (lane >= d) x += y; }
  __shared__ int wtot[4];
  if (lane == 63) wtot[w] = x;
  __syncthreads();
  int wbase = 0;
  for (int i = 0; i < w; ++i) wbase += wtot[i];
  int base = ((b > 0) ? bscan[b - 1] : 0) + wbase + (x - s4);
  if (idx + 0 < n) off[idx + 1] = base + s1;
  if (idx + 1 < n) off[idx + 2] = base + s2;
  if (idx + 2 < n) off[idx + 3] = base + s3;
  if (idx + 3 < n) off[idx + 4] = base + s4;
  if (b == 0 && t == 0) off[0] = 0;
}

// scatter into CSR-by-dst, packed (src, norm-bits); norm computed inline
__global__ void scatter_k(const int* __restrict__ ei, const float* __restrict__ attr,
                          const float* __restrict__ dis, int* __restrict__ cur,
                          int2* __restrict__ ep, int E) {
  int e = blockIdx.x * 256 + threadIdx.x;
  if (e < E) {
    int s = ei[e], d = ei[E + e];
    float nrmv = -dis[s] * attr[e] * dis[d];
    int p = atomicAdd(&cur[d], 1);
    ep[p] = make_int2(s, __float_as_int(nrmv));
  }
}

// fp32 x -> bf16
__global__ void cvt_k(const float* __restrict__ x, ushortT* __restrict__ o, int n4) {
  int i = blockIdx.x * 256 + threadIdx.x;
  if (i < n4) {
    float4 v = ((const float4*)x)[i];
    u16x4 r = {f2bf(v.x), f2bf(v.y), f2bf(v.z), f2bf(v.w)};
    ((u16x4*)o)[i] = r;
  }
}

// ---------------- sparse propagation: wave per node, lane = channel ----------------
// acc = sum_e w_e * z[src_e][lane] (bf16 z, fp32 accum)
// r = acc            if no Tprev
//   = 2*acc - Tprev  (Tprev from fp32 shadow or bf16, whichever non-null)
// out_bf always; out_f optionally (only when this T is a future Tprev)

__global__ __launch_bounds__(256) void prop_k(const ushortT* __restrict__ z,
                                              const int* __restrict__ off,
                                              const int2* __restrict__ ep,
                                              const float* __restrict__ TprevF,
                                              const ushortT* __restrict__ TprevB,
                                              ushortT* __restrict__ out_bf,
                                              float* __restrict__ out_f, int n) {
  int wid = (blockIdx.x * 256 + threadIdx.x) >> 6;
  int lane = threadIdx.x & 63;
  if (wid >= n) return;
  int s = off[wid], e = off[wid + 1];
  float a0 = 0.f, a1 = 0.f, a2 = 0.f, a3 = 0.f;
  float a4 = 0.f, a5 = 0.f, a6 = 0.f, a7 = 0.f;
  for (int base = s; base < e; base += 64) {
    int idx = base + lane;
    int2 m = (idx < e) ? ep[idx] : make_int2(0, 0);  // coalesced bulk meta load
    int cnt = min(64, e - base);
    int j = 0;
    for (; j + 8 <= cnt; j += 8) {
#define RL(t) int s##t = __builtin_amdgcn_readlane(m.x, j + t); \
              float w##t = __int_as_float(__builtin_amdgcn_readlane(m.y, j + t));
      RL(0) RL(1) RL(2) RL(3) RL(4) RL(5) RL(6) RL(7)
#undef RL
      float z0 = bf2f(z[(size_t)s0 * F + lane]);
      float z1 = bf2f(z[(size_t)s1 * F + lane]);
      float z2 = bf2f(z[(size_t)s2 * F + lane]);
      float z3 = bf2f(z[(size_t)s3 * F + lane]);
      float z4 = bf2f(z[(size_t)s4 * F + lane]);
      float z5 = bf2f(z[(size_t)s5 * F + lane]);
      float z6 = bf2f(z[(size_t)s6 * F + lane]);
      float z7 = bf2f(z[(size_t)s7 * F + lane]);
      a0 = fmaf(w0, z0, a0); a1 = fmaf(w1, z1, a1);
      a2 = fmaf(w2, z2, a2); a3 = fmaf(w3, z3, a3);
      a4 = fmaf(w4, z4, a4); a5 = fmaf(w5, z5, a5);
      a6 = fmaf(w6, z6, a6); a7 = fmaf(w7, z7, a7);
    }
    for (; j < cnt; ++j) {
      int sj = __builtin_amdgcn_readlane(m.x, j);
      float wj = __int_as_float(__builtin_amdgcn_readlane(m.y, j));
      a0 = fmaf(wj, bf2f(z[(size_t)sj * F + lane]), a0);
    }
  }
  float acc = ((a0 + a1) + (a2 + a3)) + ((a4 + a5) + (a6 + a7));
  size_t oi = (size_t)wid * F + lane;
  float r;
  if (TprevF) r = 2.f * acc - TprevF[oi];
  else if (TprevB) r = 2.f * acc - bf2f(TprevB[oi]);
  else r = acc;
  out_bf[oi] = f2bf(r);
  if (out_f) out_f[oi] = r;
}

// ---------------- weight repack: fp32 W[term][k][n] -> bf16 B-fragments ----------------
// frag fid = (term*2 + ks)*CT + ct ; lane holds B[k][n] with
// n = ct*16 + (lane&15), k = ks*32 + (lane>>4)*8 + e   (e = 0..7)

__global__ void repack_k(const float* __restrict__ W, ushortT* __restrict__ Bp, int H) {
  int t = blockIdx.x * 256 + threadIdx.x;
  int lane = t & 63, fid = t >> 6;
  int CT = H / 16;
  int nf = KT * 2 * CT;
  if (fid >= nf) return;
  int ct = fid % CT;
  int ks = (fid / CT) & 1;
  int term = fid / (CT * 2);
  int nn = ct * 16 + (lane & 15);
  int kb = ks * 32 + (lane >> 4) * 8;
  short8v out;
#pragma unroll
  for (int e = 0; e < 8; ++e)
    out[e] = (short)f2bf(W[((size_t)term * F + kb + e) * H + nn]);
  ((short8v*)Bp)[(size_t)fid * 64 + lane] = out;
}

// ------- MFMA fused-K: Y[n,H] = relu( sum_k Tk[n,64] @ W[k,64,H] + b ) -------
// block = 256 = 4 waves; each wave owns 16 rows x H cols. No LDS. bf16 in/out.

template <int H>
__global__ __launch_bounds__(256) void gemm5_mfma(const ushortT* __restrict__ T0,
                                                  const ushortT* __restrict__ T1,
                                                  const ushortT* __restrict__ T2,
                                                  const ushortT* __restrict__ T3,
                                                  const ushortT* __restrict__ T4,
                                                  const ushortT* __restrict__ Bp,
                                                  const float* __restrict__ bias,
                                                  ushortT* __restrict__ Y, int n) {
  constexpr int CT = H / 16;
  int wave = threadIdx.x >> 6;
  int lane = threadIdx.x & 63;
  int rbase = blockIdx.x * 64 + wave * 16;
  int arow = rbase + (lane & 15);
  if (arow > n - 1) arow = n - 1;  // clamp loads; stores guarded
  const short8v* bp = (const short8v*)Bp;
  const ushortT* Ts[5] = {T0, T1, T2, T3, T4};

  f32x4 acc[CT];
#pragma unroll
  for (int c = 0; c < CT; ++c) acc[c] = (f32x4){0.f, 0.f, 0.f, 0.f};

#pragma unroll
  for (int term = 0; term < KT; ++term) {
    const ushortT* T = Ts[term];
#pragma unroll
    for (int ks = 0; ks < 2; ++ks) {
      int kb = ks * 32 + (lane >> 4) * 8;
      short8v af = *(const short8v*)(T + (size_t)arow * F + kb);
      int fid0 = (term * 2 + ks) * CT;
#pragma unroll
      for (int ct = 0; ct < CT; ++ct) {
        short8v bf = bp[(size_t)(fid0 + ct) * 64 + lane];
        acc[ct] = __builtin_amdgcn_mfma_f32_16x16x32_bf16(af, bf, acc[ct], 0, 0, 0);
      }
    }
  }
  // C/D: col = lane&15, row = (lane>>4)*4 + reg
  int col0 = lane & 15;
  int rrow = rbase + (lane >> 4) * 4;
#pragma unroll
  for (int ct = 0; ct < CT; ++ct) {
    int col = ct * 16 + col0;
    float bv = bias[col];
#pragma unroll
    for (int i = 0; i < 4; ++i) {
      int gr = rrow + i;
      if (gr < n) Y[(size_t)gr * H + col] = f2bf(fmaxf(acc[ct][i] + bv, 0.f));
    }
  }
}

// ---------------- pooling + head (batch is sorted: contiguous ranges) ----------------

__global__ void gbounds_k(const int* __restrict__ batch, int* __restrict__ gstart, int n) {
  int g = threadIdx.x;
  if (g > GG) return;
  int lo = 0, hi = n;
  while (lo < hi) {
    int mid = (lo + hi) >> 1;
    if (batch[mid] < g) lo = mid + 1; else hi = mid;
  }
  gstart[g] = lo;
}

// stage 1: 64*PP blocks; block (g,p) sums its slice of graph g -> partials
__global__ __launch_bounds__(256) void pool1_k(const ushortT* __restrict__ h,
                                               const int* __restrict__ gstart,
                                               float* __restrict__ partials) {
  int g = blockIdx.x / PP, p = blockIdx.x % PP;
  int s = gstart[g], e = gstart[g + 1];
  int len = e - s;
  int ss = s + (int)((long long)len * p / PP);
  int se = s + (int)((long long)len * (p + 1) / PP);
  int tid = threadIdx.x;
  int c = tid & (H2C - 1), half = tid >> 7;
  float acc = 0.f;
  for (int i = ss + half; i < se; i += 2)
    acc += bf2f(h[(size_t)i * H2C + c]);
  __shared__ float sums[2][H2C];
  sums[half][c] = acc;
  __syncthreads();
  if (tid < H2C)
    partials[(size_t)blockIdx.x * H2C + tid] = sums[0][tid] + sums[1][tid];
}

// stage 2: 64 blocks x 128 threads; reduce partials, write hg + logits
__global__ __launch_bounds__(128) void pool2_k(const float* __restrict__ partials,
                                               const int* __restrict__ gstart,
                                               const float* __restrict__ Wl,
                                               const float* __restrict__ bl,
                                               float* __restrict__ outp) {
  int g = blockIdx.x, tid = threadIdx.x;  // tid = channel
  float s = 0.f;
  for (int p = 0; p < PP; ++p) s += partials[(size_t)(g * PP + p) * H2C + tid];
  float cntv = fmaxf((float)(gstart[g + 1] - gstart[g]), 1.f);
  float hg = s / cntv;
  outp[GG * CC + g * H2C + tid] = hg;
  __shared__ float red[2][H2C];
  red[0][tid] = hg * Wl[tid * CC + 0];
  red[1][tid] = hg * Wl[tid * CC + 1];
  __syncthreads();
  for (int st = 64; st > 0; st >>= 1) {
    if (tid < st) { red[0][tid] += red[0][tid + st]; red[1][tid] += red[1][tid + st]; }
    __syncthreads();
  }
  if (tid == 0) {
    outp[g * CC + 0] = red[0][0] + bl[0];
    outp[g * CC + 1] = red[1][0] + bl[1];
  }
}

// ---------------- driver ----------------

extern "C" void kernel_launch(void* const* d_in, const int* in_sizes, int n_in,
                              void* d_out, int out_size, void* d_ws, size_t ws_size,
                              hipStream_t stream) {
  const float* x    = (const float*)d_in[0];
  const int*   ei   = (const int*)d_in[1];
  const float* attr = (const float*)d_in[2];
  const int*   batch= (const int*)d_in[3];
  const float* W1 = (const float*)d_in[4];
  const float* b1 = (const float*)d_in[5];
  const float* W2 = (const float*)d_in[6];
  const float* b2 = (const float*)d_in[7];
  const float* W3 = (const float*)d_in[8];
  const float* b3 = (const float*)d_in[9];
  const float* Wl = (const float*)d_in[10];
  const float* bl = (const float*)d_in[11];
  float* outp = (float*)d_out;

  const int N = in_sizes[3];
  const int E = in_sizes[2];

  char* p = (char*)d_ws;
  auto alloc = [&](size_t bytes) {
    char* r = p;
    p += (bytes + 255) & ~(size_t)255;
    return r;
  };
  float* deg   = (float*)alloc((size_t)N * 4);
  int*   cnt   = (int*)alloc((size_t)N * 4);
  int*   off   = (int*)alloc((size_t)(N + 1) * 4);
  int*   cur   = (int*)alloc((size_t)N * 4);
  int2*  ep    = (int2*)alloc((size_t)E * 8);
  int*   bsum  = (int*)alloc(4096);
  int*   gstart= (int*)alloc((size_t)(GG + 1) * 4);
  ushortT* Bp1 = (ushortT*)alloc((size_t)KT * 2 * 4 * 64 * 8 * 2);
  ushortT* Bp2 = (ushortT*)alloc((size_t)KT * 2 * 4 * 64 * 8 * 2);
  ushortT* Bp3 = (ushortT*)alloc((size_t)KT * 2 * 8 * 64 * 8 * 2);
  // bf16 node matrices (N x 64)
  ushortT* X0  = (ushortT*)alloc((size_t)N * F * 2);
  ushortT* Abf = (ushortT*)alloc((size_t)N * F * 2);
  ushortT* Bbf = (ushortT*)alloc((size_t)N * F * 2);
  ushortT* Cbf = (ushortT*)alloc((size_t)N * F * 2);
  ushortT* Dbf = (ushortT*)alloc((size_t)N * F * 2);
  ushortT* Y1  = (ushortT*)alloc((size_t)N * F * 2);
  ushortT* Y2  = (ushortT*)alloc((size_t)N * F * 2);
  ushortT* Y3  = (ushortT*)alloc((size_t)N * H2C * 2);
  // fp32 shadows for T1, T2 (used as Tprev)
  float* Af = (float*)alloc((size_t)N * F * 4);
  float* Bf = (float*)alloc((size_t)N * F * 4);
  float* partials = (float*)alloc((size_t)GG * PP * H2C * 4);

  hipMemsetAsync(deg, 0, (size_t)N * 4, stream);
  hipMemsetAsync(cnt, 0, (size_t)N * 4, stream);

  int eb = (E + 255) / 256;
  int nb = (N + 255) / 256;
  int sb = (N + 1023) / 1024;

  // weight repacks + x conversion (independent of graph preprocessing)
  repack_k<<<(KT * 2 * 4 * 64 + 255) / 256, 256, 0, stream>>>(W1, Bp1, 64);
  repack_k<<<(KT * 2 * 4 * 64 + 255) / 256, 256, 0, stream>>>(W2, Bp2, 64);
  repack_k<<<(KT * 2 * 8 * 64 + 255) / 256, 256, 0, stream>>>(W3, Bp3, 128);
  cvt_k<<<((N * F / 4) + 255) / 256, 256, 0, stream>>>(x, X0, N * F / 4);

  pre_hist<<<eb, 256, 0, stream>>>(ei, attr, deg, cnt, E);
  dis_k<<<nb, 256, 0, stream>>>(deg, N);
  scan_a<<<sb, 256, 0, stream>>>(cnt, bsum, N);
  scan_b<<<1, 64, 0, stream>>>(bsum, sb);
  scan_c<<<sb, 256, 0, stream>>>(cnt, bsum, off, N);
  hipMemcpyAsync(cur, off, (size_t)N * 4, hipMemcpyDeviceToDevice, stream);
  scatter_k<<<eb, 256, 0, stream>>>(ei, attr, deg, cur, ep, E);
  gbounds_k<<<1, 128, 0, stream>>>(batch, gstart, N);

  int pb = (N + 3) / 4;
  auto prop = [&](const ushortT* z, const float* TprevF, const ushortT* TprevB,
                  ushortT* obf, float* of) {
    prop_k<<<pb, 256, 0, stream>>>(z, off, ep, TprevF, TprevB, obf, of, N);
  };

  // layer: T0 bf16 (+ optional fp32 T0f for layer-1 where x is fp32)
  auto run_layer = [&](const ushortT* T0, const float* T0f, const ushortT* Bpk,
                       const float* bk, ushortT* Yout, int Hout) {
    prop(T0, nullptr, nullptr, Abf, Af);              // T1 (keep fp32 shadow)
    prop(Abf, T0f, T0f ? nullptr : T0, Bbf, Bf);      // T2 = 2LT1 - T0 (shadow)
    prop(Bbf, Af, nullptr, Cbf, nullptr);             // T3 = 2LT2 - T1
    prop(Cbf, Bf, nullptr, Dbf, nullptr);             // T4 = 2LT3 - T2
    if (Hout == 64)
      gemm5_mfma<64><<<(N + 63) / 64, 256, 0, stream>>>(T0, Abf, Bbf, Cbf, Dbf,
                                                        Bpk, bk, Yout, N);
    else
      gemm5_mfma<128><<<(N + 63) / 64, 256, 0, stream>>>(T0, Abf, Bbf, Cbf, Dbf,
                                                         Bpk, bk, Yout, N);
  };

  run_layer(X0, x,       Bp1, b1, Y1, 64);
  run_layer(Y1, nullptr, Bp2, b2, Y2, 64);
  run_layer(Y2, nullptr, Bp3, b3, Y3, 128);

  pool1_k<<<GG * PP, 256, 0, stream>>>(Y3, gstart, partials);
  pool2_k<<<GG, 128, 0, stream>>>(partials, gstart, Wl, bl, outp);
}

// Round 5
// 522.979 us; speedup vs baseline: 3.5295x; 1.0418x over previous
//
#include <hip/hip_runtime.h>
#include <hip/hip_fp16.h>

// ChebConv GNN: 3x ChebConv(K=5) + ReLU, global mean pool, linear head.
// N=50000, E=800000, F_IN=H1=64, H2=128, G=64, C=2.
// R5: 4-way replicated atomic histograms + rank-trick (atomic-free scatter),
//     4B packed edge meta (u16 src + fp16 norm), no fp32 shadows.
// Assumes N < 65536 (u16 src) and per-replica in-degree < 65536 (u16 rank).

constexpr int F = 64;    // F_IN = H1
constexpr int H2C = 128;
constexpr int GG = 64;   // graphs
constexpr int CC = 2;    // classes
constexpr int KT = 5;    // Chebyshev terms
constexpr int PP = 16;   // pool partial blocks per graph
constexpr int RR = 4;    // histogram replicas

typedef __attribute__((ext_vector_type(8))) short short8v;
typedef __attribute__((ext_vector_type(4))) float f32x4;
typedef unsigned short ushortT;
typedef __attribute__((ext_vector_type(4))) unsigned short u16x4;

__device__ inline ushortT f2bf(float f) {
  unsigned u = __float_as_uint(f);
  u = (u + 0x7fffu + ((u >> 16) & 1u)) >> 16;
  return (ushortT)u;
}
__device__ inline float bf2f(ushortT u) {
  return __uint_as_float((unsigned)u << 16);
}
__device__ inline float h2f_bits(unsigned short b) {
  __half_raw hr; hr.x = b;
  return __half2float(*reinterpret_cast<__half*>(&hr));
}
__device__ inline unsigned short f2h_bits(float v) {
  __half h = __float2half(v);
  return reinterpret_cast<__half_raw*>(&h)->x;
}

// ---------------- edge preprocessing ----------------

// replicated: degR[r][src] += attr ; rank = cntR[r][dst]++ ; rankr[e] = (r<<16)|rank
__global__ void pre_hist(const int* __restrict__ ei, const float* __restrict__ attr,
                         float* __restrict__ degR, int* __restrict__ cntR,
                         int* __restrict__ rankr, int E, int N) {
  int e = blockIdx.x * 256 + threadIdx.x;
  if (e < E) {
    int r = (threadIdx.x >> 6) & (RR - 1);
    int s = ei[e], d = ei[E + e];
    atomicAdd(&degR[r * N + s], attr[e]);
    int rk = atomicAdd(&cntR[r * N + d], 1);
    rankr[e] = (r << 16) | rk;
  }
}

__global__ void dis_k(const float* __restrict__ degR, float* __restrict__ dis, int n) {
  int i = blockIdx.x * 256 + threadIdx.x;
  if (i < n) {
    float d = degR[i] + degR[n + i] + degR[2 * n + i] + degR[3 * n + i];
    dis[i] = d > 0.f ? rsqrtf(d) : 0.f;
  }
}

__global__ void sumcnt_k(const int* __restrict__ cntR, int* __restrict__ cnt, int n) {
  int i = blockIdx.x * 256 + threadIdx.x;
  if (i < n) cnt[i] = cntR[i] + cntR[n + i] + cntR[2 * n + i] + cntR[3 * n + i];
}

// ---- hierarchical scan: off[i+1] = inclusive sum of cnt[0..i], off[0]=0 ----

__global__ __launch_bounds__(256) void scan_a(const int* __restrict__ cnt,
                                              int* __restrict__ bsum, int n) {
  int t = threadIdx.x, lane = t & 63, w = t >> 6;
  int base = blockIdx.x * 1024 + t * 4;
  int s = 0;
#pragma unroll
  for (int j = 0; j < 4; ++j) { int i = base + j; if (i < n) s += cnt[i]; }
#pragma unroll
  for (int d = 1; d < 64; d <<= 1) s += __shfl_down(s, d, 64);
  __shared__ int ws[4];
  if (lane == 0) ws[w] = s;
  __syncthreads();
  if (t == 0) bsum[blockIdx.x] = ws[0] + ws[1] + ws[2] + ws[3];
}

__global__ void scan_b(int* __restrict__ bsum, int nb) {
  if (threadIdx.x == 0) {
    int acc = 0;
    for (int i = 0; i < nb; ++i) { acc += bsum[i]; bsum[i] = acc; }
  }
}

__global__ __launch_bounds__(256) void scan_c(const int* __restrict__ cnt,
                                              const int* __restrict__ bscan,
                                              int* __restrict__ off, int n) {
  int b = blockIdx.x, t = threadIdx.x;
  int lane = t & 63, w = t >> 6;
  int idx = b * 1024 + t * 4;
  int v[4];
#pragma unroll
  for (int j = 0; j < 4; ++j) { int i = idx + j; v[j] = (i < n) ? cnt[i] : 0; }
  int s1 = v[0], s2 = s1 + v[1], s3 = s2 + v[2], s4 = s3 + v[3];
  int x = s4;
#pragma unroll
  for (int d = 1; d < 64; d <<= 1) { int y = __shfl_up(x, d, 64); if (lane >= d) x += y; }
  __shared__ int wtot[4];
  if (lane == 63) wtot[w] = x;
  __syncthreads();
  int wbase = 0;
  for (int i = 0; i < w; ++i) wbase += wtot[i];
  int base = ((b > 0) ? bscan[b - 1] : 0) + wbase + (x - s4);
  if (idx + 0 < n) off[idx + 1] = base + s1;
  if (idx + 1 < n) off[idx + 2] = base + s2;
  if (idx + 2 < n) off[idx + 3] = base + s3;
  if (idx + 3 < n) off[idx + 4] = base + s4;
  if (b == 0 && t == 0) off[0] = 0;
}

// per-replica base offsets: roff[r][d] = off[d] + sum_{r'<r} cntR[r'][d]
__global__ void roff_k(const int* __restrict__ off, const int* __restrict__ cntR,
                       int* __restrict__ roff, int n) {
  int i = blockIdx.x * 256 + threadIdx.x;
  if (i < n) {
    int b = off[i];
#pragma unroll
    for (int r = 0; r < RR; ++r) { roff[r * n + i] = b; b += cntR[r * n + i]; }
  }
}

// atomic-free scatter: pos = roff[r][dst] + rank; meta packed 4B (fp16 norm | u16 src)
__global__ void scatter_k(const int* __restrict__ ei, const float* __restrict__ attr,
                          const float* __restrict__ dis, const int* __restrict__ rankr,
                          const int* __restrict__ roff, unsigned* __restrict__ ep4,
                          int E, int N) {
  int e = blockIdx.x * 256 + threadIdx.x;
  if (e < E) {
    int s = ei[e], d = ei[E + e];
    unsigned v = (unsigned)rankr[e];
    int r = v >> 16, rk = v & 0xFFFF;
    int pos = roff[r * N + d] + rk;
    float nv = -dis[s] * attr[e] * dis[d];
    ep4[pos] = ((unsigned)f2h_bits(nv) << 16) | (unsigned)(s & 0xFFFF);
  }
}

// fp32 x -> bf16
__global__ void cvt_k(const float* __restrict__ x, ushortT* __restrict__ o, int n4) {
  int i = blockIdx.x * 256 + threadIdx.x;
  if (i < n4) {
    float4 v = ((const float4*)x)[i];
    u16x4 r = {f2bf(v.x), f2bf(v.y), f2bf(v.z), f2bf(v.w)};
    ((u16x4*)o)[i] = r;
  }
}

// ---------------- sparse propagation: wave per node, lane = channel ----------------
// acc = sum_e w_e * z[src_e][lane] (bf16 z, fp16 w, fp32 accum)
// r = acc (no Tprev) | 2*acc - TprevF (fp32) | 2*acc - TprevB (bf16)

__global__ __launch_bounds__(256) void prop_k(const ushortT* __restrict__ z,
                                              const int* __restrict__ off,
                                              const unsigned* __restrict__ ep4,
                                              const float* __restrict__ TprevF,
                                              const ushortT* __restrict__ TprevB,
                                              ushortT* __restrict__ out_bf, int n) {
  int wid = (blockIdx.x * 256 + threadIdx.x) >> 6;
  int lane = threadIdx.x & 63;
  if (wid >= n) return;
  int s = off[wid], e = off[wid + 1];
  float a0 = 0.f, a1 = 0.f, a2 = 0.f, a3 = 0.f;
  float a4 = 0.f, a5 = 0.f, a6 = 0.f, a7 = 0.f;
  for (int base = s; base < e; base += 64) {
    int idx = base + lane;
    unsigned m = (idx < e) ? ep4[idx] : 0u;  // coalesced bulk meta load
    int cnt = min(64, e - base);
    int j = 0;
    for (; j + 8 <= cnt; j += 8) {
#define RL(t) unsigned m##t = (unsigned)__builtin_amdgcn_readlane((int)m, j + t); \
              int s##t = m##t & 0xFFFF;                                           \
              float w##t = h2f_bits((unsigned short)(m##t >> 16));
      RL(0) RL(1) RL(2) RL(3) RL(4) RL(5) RL(6) RL(7)
#undef RL
      float z0 = bf2f(z[(size_t)s0 * F + lane]);
      float z1 = bf2f(z[(size_t)s1 * F + lane]);
      float z2 = bf2f(z[(size_t)s2 * F + lane]);
      float z3 = bf2f(z[(size_t)s3 * F + lane]);
      float z4 = bf2f(z[(size_t)s4 * F + lane]);
      float z5 = bf2f(z[(size_t)s5 * F + lane]);
      float z6 = bf2f(z[(size_t)s6 * F + lane]);
      float z7 = bf2f(z[(size_t)s7 * F + lane]);
      a0 = fmaf(w0, z0, a0); a1 = fmaf(w1, z1, a1);
      a2 = fmaf(w2, z2, a2); a3 = fmaf(w3, z3, a3);
      a4 = fmaf(w4, z4, a4); a5 = fmaf(w5, z5, a5);
      a6 = fmaf(w6, z6, a6); a7 = fmaf(w7, z7, a7);
    }
    for (; j < cnt; ++j) {
      unsigned mj = (unsigned)__builtin_amdgcn_readlane((int)m, j);
      int sj = mj & 0xFFFF;
      float wj = h2f_bits((unsigned short)(mj >> 16));
      a0 = fmaf(wj, bf2f(z[(size_t)sj * F + lane]), a0);
    }
  }
  float acc = ((a0 + a1) + (a2 + a3)) + ((a4 + a5) + (a6 + a7));
  size_t oi = (size_t)wid * F + lane;
  float r;
  if (TprevF) r = 2.f * acc - TprevF[oi];
  else if (TprevB) r = 2.f * acc - bf2f(TprevB[oi]);
  else r = acc;
  out_bf[oi] = f2bf(r);
}

// ---------------- weight repack: fp32 W[term][k][n] -> bf16 B-fragments ----------------
// frag fid = (term*2 + ks)*CT + ct ; lane holds B[k][n] with
// n = ct*16 + (lane&15), k = ks*32 + (lane>>4)*8 + e   (e = 0..7)

__global__ void repack_k(const float* __restrict__ W, ushortT* __restrict__ Bp, int H) {
  int t = blockIdx.x * 256 + threadIdx.x;
  int lane = t & 63, fid = t >> 6;
  int CT = H / 16;
  int nf = KT * 2 * CT;
  if (fid >= nf) return;
  int ct = fid % CT;
  int ks = (fid / CT) & 1;
  int term = fid / (CT * 2);
  int nn = ct * 16 + (lane & 15);
  int kb = ks * 32 + (lane >> 4) * 8;
  short8v out;
#pragma unroll
  for (int e = 0; e < 8; ++e)
    out[e] = (short)f2bf(W[((size_t)term * F + kb + e) * H + nn]);
  ((short8v*)Bp)[(size_t)fid * 64 + lane] = out;
}

// ------- MFMA fused-K: Y[n,H] = relu( sum_k Tk[n,64] @ W[k,64,H] + b ) -------
// block = 256 = 4 waves; each wave owns 16 rows x H cols. No LDS. bf16 in/out.

template <int H>
__global__ __launch_bounds__(256) void gemm5_mfma(const ushortT* __restrict__ T0,
                                                  const ushortT* __restrict__ T1,
                                                  const ushortT* __restrict__ T2,
                                                  const ushortT* __restrict__ T3,
                                                  const ushortT* __restrict__ T4,
                                                  const ushortT* __restrict__ Bp,
                                                  const float* __restrict__ bias,
                                                  ushortT* __restrict__ Y, int n) {
  constexpr int CT = H / 16;
  int wave = threadIdx.x >> 6;
  int lane = threadIdx.x & 63;
  int rbase = blockIdx.x * 64 + wave * 16;
  int arow = rbase + (lane & 15);
  if (arow > n - 1) arow = n - 1;  // clamp loads; stores guarded
  const short8v* bp = (const short8v*)Bp;
  const ushortT* Ts[5] = {T0, T1, T2, T3, T4};

  f32x4 acc[CT];
#pragma unroll
  for (int c = 0; c < CT; ++c) acc[c] = (f32x4){0.f, 0.f, 0.f, 0.f};

#pragma unroll
  for (int term = 0; term < KT; ++term) {
    const ushortT* T = Ts[term];
#pragma unroll
    for (int ks = 0; ks < 2; ++ks) {
      int kb = ks * 32 + (lane >> 4) * 8;
      short8v af = *(const short8v*)(T + (size_t)arow * F + kb);
      int fid0 = (term * 2 + ks) * CT;
#pragma unroll
      for (int ct = 0; ct < CT; ++ct) {
        short8v bf = bp[(size_t)(fid0 + ct) * 64 + lane];
        acc[ct] = __builtin_amdgcn_mfma_f32_16x16x32_bf16(af, bf, acc[ct], 0, 0, 0);
      }
    }
  }
  // C/D: col = lane&15, row = (lane>>4)*4 + reg
  int col0 = lane & 15;
  int rrow = rbase + (lane >> 4) * 4;
#pragma unroll
  for (int ct = 0; ct < CT; ++ct) {
    int col = ct * 16 + col0;
    float bv = bias[col];
#pragma unroll
    for (int i = 0; i < 4; ++i) {
      int gr = rrow + i;
      if (gr < n) Y[(size_t)gr * H + col] = f2bf(fmaxf(acc[ct][i] + bv, 0.f));
    }
  }
}

// ---------------- pooling + head (batch is sorted: contiguous ranges) ----------------

__global__ void gbounds_k(const int* __restrict__ batch, int* __restrict__ gstart, int n) {
  int g = threadIdx.x;
  if (g > GG) return;
  int lo = 0, hi = n;
  while (lo < hi) {
    int mid = (lo + hi) >> 1;
    if (batch[mid] < g) lo = mid + 1; else hi = mid;
  }
  gstart[g] = lo;
}

// stage 1: 64*PP blocks; block (g,p) sums its slice of graph g -> partials
__global__ __launch_bounds__(256) void pool1_k(const ushortT* __restrict__ h,
                                               const int* __restrict__ gstart,
                                               float* __restrict__ partials) {
  int g = blockIdx.x / PP, p = blockIdx.x % PP;
  int s = gstart[g], e = gstart[g + 1];
  int len = e - s;
  int ss = s + (int)((long long)len * p / PP);
  int se = s + (int)((long long)len * (p + 1) / PP);
  int tid = threadIdx.x;
  int c = tid & (H2C - 1), half = tid >> 7;
  float acc = 0.f;
  for (int i = ss + half; i < se; i += 2)
    acc += bf2f(h[(size_t)i * H2C + c]);
  __shared__ float sums[2][H2C];
  sums[half][c] = acc;
  __syncthreads();
  if (tid < H2C)
    partials[(size_t)blockIdx.x * H2C + tid] = sums[0][tid] + sums[1][tid];
}

// stage 2: 64 blocks x 128 threads; reduce partials, write hg + logits
__global__ __launch_bounds__(128) void pool2_k(const float* __restrict__ partials,
                                               const int* __restrict__ gstart,
                                               const float* __restrict__ Wl,
                                               const float* __restrict__ bl,
                                               float* __restrict__ outp) {
  int g = blockIdx.x, tid = threadIdx.x;  // tid = channel
  float s = 0.f;
  for (int p = 0; p < PP; ++p) s += partials[(size_t)(g * PP + p) * H2C + tid];
  float cntv = fmaxf((float)(gstart[g + 1] - gstart[g]), 1.f);
  float hg = s / cntv;
  outp[GG * CC + g * H2C + tid] = hg;
  __shared__ float red[2][H2C];
  red[0][tid] = hg * Wl[tid * CC + 0];
  red[1][tid] = hg * Wl[tid * CC + 1];
  __syncthreads();
  for (int st = 64; st > 0; st >>= 1) {
    if (tid < st) { red[0][tid] += red[0][tid + st]; red[1][tid] += red[1][tid + st]; }
    __syncthreads();
  }
  if (tid == 0) {
    outp[g * CC + 0] = red[0][0] + bl[0];
    outp[g * CC + 1] = red[1][0] + bl[1];
  }
}

// ---------------- driver ----------------

extern "C" void kernel_launch(void* const* d_in, const int* in_sizes, int n_in,
                              void* d_out, int out_size, void* d_ws, size_t ws_size,
                              hipStream_t stream) {
  const float* x    = (const float*)d_in[0];
  const int*   ei   = (const int*)d_in[1];
  const float* attr = (const float*)d_in[2];
  const int*   batch= (const int*)d_in[3];
  const float* W1 = (const float*)d_in[4];
  const float* b1 = (const float*)d_in[5];
  const float* W2 = (const float*)d_in[6];
  const float* b2 = (const float*)d_in[7];
  const float* W3 = (const float*)d_in[8];
  const float* b3 = (const float*)d_in[9];
  const float* Wl = (const float*)d_in[10];
  const float* bl = (const float*)d_in[11];
  float* outp = (float*)d_out;

  const int N = in_sizes[3];
  const int E = in_sizes[2];

  char* p = (char*)d_ws;
  auto alloc = [&](size_t bytes) {
    char* r = p;
    p += (bytes + 255) & ~(size_t)255;
    return r;
  };
  float* degR  = (float*)alloc((size_t)RR * N * 4);
  int*   cntR  = (int*)alloc((size_t)RR * N * 4);
  float* dis   = (float*)alloc((size_t)N * 4);
  int*   cnt   = (int*)alloc((size_t)N * 4);
  int*   off   = (int*)alloc((size_t)(N + 1) * 4);
  int*   roff  = (int*)alloc((size_t)RR * N * 4);
  int*   rankr = (int*)alloc((size_t)E * 4);
  unsigned* ep4 = (unsigned*)alloc((size_t)E * 4);
  int*   bsum  = (int*)alloc(4096);
  int*   gstart= (int*)alloc((size_t)(GG + 1) * 4);
  ushortT* Bp1 = (ushortT*)alloc((size_t)KT * 2 * 4 * 64 * 8 * 2);
  ushortT* Bp2 = (ushortT*)alloc((size_t)KT * 2 * 4 * 64 * 8 * 2);
  ushortT* Bp3 = (ushortT*)alloc((size_t)KT * 2 * 8 * 64 * 8 * 2);
  // bf16 node matrices (N x 64)
  ushortT* X0  = (ushortT*)alloc((size_t)N * F * 2);
  ushortT* Abf = (ushortT*)alloc((size_t)N * F * 2);
  ushortT* Bbf = (ushortT*)alloc((size_t)N * F * 2);
  ushortT* Cbf = (ushortT*)alloc((size_t)N * F * 2);
  ushortT* Dbf = (ushortT*)alloc((size_t)N * F * 2);
  ushortT* Y1  = (ushortT*)alloc((size_t)N * F * 2);
  ushortT* Y2  = (ushortT*)alloc((size_t)N * F * 2);
  ushortT* Y3  = (ushortT*)alloc((size_t)N * H2C * 2);
  float* partials = (float*)alloc((size_t)GG * PP * H2C * 4);

  hipMemsetAsync(degR, 0, (size_t)RR * N * 4, stream);
  hipMemsetAsync(cntR, 0, (size_t)RR * N * 4, stream);

  int eb = (E + 255) / 256;
  int nb = (N + 255) / 256;
  int sb = (N + 1023) / 1024;

  // weight repacks + x conversion (independent of graph preprocessing)
  repack_k<<<(KT * 2 * 4 * 64 + 255) / 256, 256, 0, stream>>>(W1, Bp1, 64);
  repack_k<<<(KT * 2 * 4 * 64 + 255) / 256, 256, 0, stream>>>(W2, Bp2, 64);
  repack_k<<<(KT * 2 * 8 * 64 + 255) / 256, 256, 0, stream>>>(W3, Bp3, 128);
  cvt_k<<<((N * F / 4) + 255) / 256, 256, 0, stream>>>(x, X0, N * F / 4);

  pre_hist<<<eb, 256, 0, stream>>>(ei, attr, degR, cntR, rankr, E, N);
  dis_k<<<nb, 256, 0, stream>>>(degR, dis, N);
  sumcnt_k<<<nb, 256, 0, stream>>>(cntR, cnt, N);
  scan_a<<<sb, 256, 0, stream>>>(cnt, bsum, N);
  scan_b<<<1, 64, 0, stream>>>(bsum, sb);
  scan_c<<<sb, 256, 0, stream>>>(cnt, bsum, off, N);
  roff_k<<<nb, 256, 0, stream>>>(off, cntR, roff, N);
  scatter_k<<<eb, 256, 0, stream>>>(ei, attr, dis, rankr, roff, ep4, E, N);
  gbounds_k<<<1, 128, 0, stream>>>(batch, gstart, N);

  int pb = (N + 3) / 4;
  auto prop = [&](const ushortT* z, const float* TprevF, const ushortT* TprevB,
                  ushortT* obf) {
    prop_k<<<pb, 256, 0, stream>>>(z, off, ep4, TprevF, TprevB, obf, N);
  };

  // layer: T0 bf16 (+ optional fp32 T0f for layer-1 where x is fp32)
  auto run_layer = [&](const ushortT* T0, const float* T0f, const ushortT* Bpk,
                       const float* bk, ushortT* Yout, int Hout) {
    prop(T0, nullptr, nullptr, Abf);              // T1 = L T0
    prop(Abf, T0f, T0f ? nullptr : T0, Bbf);      // T2 = 2L T1 - T0
    prop(Bbf, nullptr, Abf, Cbf);                 // T3 = 2L T2 - T1
    prop(Cbf, nullptr, Bbf, Dbf);                 // T4 = 2L T3 - T2
    if (Hout == 64)
      gemm5_mfma<64><<<(N + 63) / 64, 256, 0, stream>>>(T0, Abf, Bbf, Cbf, Dbf,
                                                        Bpk, bk, Yout, N);
    else
      gemm5_mfma<128><<<(N + 63) / 64, 256, 0, stream>>>(T0, Abf, Bbf, Cbf, Dbf,
                                                         Bpk, bk, Yout, N);
  };

  run_layer(X0, x,       Bp1, b1, Y1, 64);
  run_layer(Y1, nullptr, Bp2, b2, Y2, 64);
  run_layer(Y2, nullptr, Bp3, b3, Y3, 128);

  pool1_k<<<GG * PP, 256, 0, stream>>>(Y3, gstart, partials);
  pool2_k<<<GG, 128, 0, stream>>>(partials, gstart, Wl, bl, outp);
}

// Round 6
// 452.883 us; speedup vs baseline: 4.0758x; 1.1548x over previous
//
#include <hip/hip_runtime.h>
#include <hip/hip_fp16.h>

// ChebConv GNN: 3x ChebConv(K=5) + ReLU, global mean pool, linear head.
// N=50000, E=800000, F_IN=H1=64, H2=128, G=64, C=2.
// R6: prop rewritten as 8-row-per-instruction gather (lane = stream x octet,
//     ushort8 loads, shfl-xor reduce); pre_hist de-replicated with rank
//     captured from the cnt atomic return (scatter stays atomic-free).
// Assumes N < 65536 (u16 src) and in-degree < 65536 (u16 rank).

constexpr int F = 64;    // F_IN = H1
constexpr int H2C = 128;
constexpr int GG = 64;   // graphs
constexpr int CC = 2;    // classes
constexpr int KT = 5;    // Chebyshev terms
constexpr int PP = 16;   // pool partial blocks per graph

typedef __attribute__((ext_vector_type(8))) short short8v;
typedef __attribute__((ext_vector_type(4))) float f32x4;
typedef unsigned short ushortT;
typedef __attribute__((ext_vector_type(4))) unsigned short u16x4;
typedef __attribute__((ext_vector_type(8))) unsigned short u16x8;

__device__ inline ushortT f2bf(float f) {
  unsigned u = __float_as_uint(f);
  u = (u + 0x7fffu + ((u >> 16) & 1u)) >> 16;
  return (ushortT)u;
}
__device__ inline float bf2f(ushortT u) {
  return __uint_as_float((unsigned)u << 16);
}
__device__ inline float h2f_bits(unsigned short b) {
  __half_raw hr; hr.x = b;
  return __half2float(*reinterpret_cast<__half*>(&hr));
}
__device__ inline unsigned short f2h_bits(float v) {
  __half h = __float2half(v);
  return reinterpret_cast<__half_raw*>(&h)->x;
}

// ---------------- edge preprocessing ----------------

// deg[src] += attr ; rank = cnt[dst]++ (rank captured for atomic-free scatter)
__global__ void pre_hist(const int* __restrict__ ei, const float* __restrict__ attr,
                         float* __restrict__ deg, int* __restrict__ cnt,
                         ushortT* __restrict__ rankr, int E) {
  int e = blockIdx.x * 256 + threadIdx.x;
  if (e < E) {
    atomicAdd(&deg[ei[e]], attr[e]);
    int rk = atomicAdd(&cnt[ei[E + e]], 1);
    rankr[e] = (ushortT)rk;
  }
}

__global__ void dis_k(const float* __restrict__ deg, float* __restrict__ dis, int n) {
  int i = blockIdx.x * 256 + threadIdx.x;
  if (i < n) { float d = deg[i]; dis[i] = d > 0.f ? rsqrtf(d) : 0.f; }
}

// ---- hierarchical scan: off[i+1] = inclusive sum of cnt[0..i], off[0]=0 ----

__global__ __launch_bounds__(256) void scan_a(const int* __restrict__ cnt,
                                              int* __restrict__ bsum, int n) {
  int t = threadIdx.x, lane = t & 63, w = t >> 6;
  int base = blockIdx.x * 1024 + t * 4;
  int s = 0;
#pragma unroll
  for (int j = 0; j < 4; ++j) { int i = base + j; if (i < n) s += cnt[i]; }
#pragma unroll
  for (int d = 1; d < 64; d <<= 1) s += __shfl_down(s, d, 64);
  __shared__ int ws[4];
  if (lane == 0) ws[w] = s;
  __syncthreads();
  if (t == 0) bsum[blockIdx.x] = ws[0] + ws[1] + ws[2] + ws[3];
}

__global__ void scan_b(int* __restrict__ bsum, int nb) {
  if (threadIdx.x == 0) {
    int acc = 0;
    for (int i = 0; i < nb; ++i) { acc += bsum[i]; bsum[i] = acc; }
  }
}

__global__ __launch_bounds__(256) void scan_c(const int* __restrict__ cnt,
                                              const int* __restrict__ bscan,
                                              int* __restrict__ off, int n) {
  int b = blockIdx.x, t = threadIdx.x;
  int lane = t & 63, w = t >> 6;
  int idx = b * 1024 + t * 4;
  int v[4];
#pragma unroll
  for (int j = 0; j < 4; ++j) { int i = idx + j; v[j] = (i < n) ? cnt[i] : 0; }
  int s1 = v[0], s2 = s1 + v[1], s3 = s2 + v[2], s4 = s3 + v[3];
  int x = s4;
#pragma unroll
  for (int d = 1; d < 64; d <<= 1) { int y = __shfl_up(x, d, 64); if (lane >= d) x += y; }
  __shared__ int wtot[4];
  if (lane == 63) wtot[w] = x;
  __syncthreads();
  int wbase = 0;
  for (int i = 0; i < w; ++i) wbase += wtot[i];
  int base = ((b > 0) ? bscan[b - 1] : 0) + wbase + (x - s4);
  if (idx + 0 < n) off[idx + 1] = base + s1;
  if (idx + 1 < n) off[idx + 2] = base + s2;
  if (idx + 2 < n) off[idx + 3] = base + s3;
  if (idx + 3 < n) off[idx + 4] = base + s4;
  if (b == 0 && t == 0) off[0] = 0;
}

// atomic-free scatter: pos = off[dst] + rank; meta packed 4B (fp16 norm | u16 src)
__global__ void scatter_k(const int* __restrict__ ei, const float* __restrict__ attr,
                          const float* __restrict__ dis,
                          const ushortT* __restrict__ rankr,
                          const int* __restrict__ off, unsigned* __restrict__ ep4,
                          int E) {
  int e = blockIdx.x * 256 + threadIdx.x;
  if (e < E) {
    int s = ei[e], d = ei[E + e];
    int pos = off[d] + (int)rankr[e];
    float nv = -dis[s] * attr[e] * dis[d];
    ep4[pos] = ((unsigned)f2h_bits(nv) << 16) | (unsigned)(s & 0xFFFF);
  }
}

// fp32 x -> bf16
__global__ void cvt_k(const float* __restrict__ x, ushortT* __restrict__ o, int n4) {
  int i = blockIdx.x * 256 + threadIdx.x;
  if (i < n4) {
    float4 v = ((const float4*)x)[i];
    u16x4 r = {f2bf(v.x), f2bf(v.y), f2bf(v.z), f2bf(v.w)};
    ((u16x4*)o)[i] = r;
  }
}

// ---------------- sparse propagation: wave per node ----------------
// lane = (stream t = lane>>3, channel-octet sub = lane&7).
// Each wave-instruction gathers 8 rows (one per stream) x 16B (8 bf16 ch).
// Inactive edge slots auto-mask: guarded meta load yields m=0 -> w=0, src=0.

__global__ __launch_bounds__(256) void prop_k(const ushortT* __restrict__ z,
                                              const int* __restrict__ off,
                                              const unsigned* __restrict__ ep4,
                                              const float* __restrict__ TprevF,
                                              const ushortT* __restrict__ TprevB,
                                              ushortT* __restrict__ out_bf, int n) {
  int wid = (blockIdx.x * 256 + threadIdx.x) >> 6;
  int lane = threadIdx.x & 63;
  if (wid >= n) return;
  int s = off[wid], e = off[wid + 1];
  int sub = lane & 7;
  int t = lane >> 3;
  float acc[8];
#pragma unroll
  for (int c = 0; c < 8; ++c) acc[c] = 0.f;
  for (int base = s; base < e; base += 64) {
    int idx = base + lane;
    unsigned m = (idx < e) ? ep4[idx] : 0u;  // coalesced bulk meta load
    int cntc = min(64, e - base);
    for (int j = 0; j < cntc; j += 16) {
      unsigned me0 = (unsigned)__shfl((int)m, j + t, 64);
      unsigned me1 = (unsigned)__shfl((int)m, j + 8 + t, 64);
      float w0 = h2f_bits((unsigned short)(me0 >> 16));
      float w1 = h2f_bits((unsigned short)(me1 >> 16));
      int s0 = (int)(me0 & 0xFFFF);
      int s1 = (int)(me1 & 0xFFFF);
      u16x8 v0 = *(const u16x8*)(z + ((size_t)s0 << 6) + sub * 8);
      u16x8 v1 = *(const u16x8*)(z + ((size_t)s1 << 6) + sub * 8);
#pragma unroll
      for (int c = 0; c < 8; ++c) acc[c] = fmaf(w0, bf2f(v0[c]), acc[c]);
#pragma unroll
      for (int c = 0; c < 8; ++c) acc[c] = fmaf(w1, bf2f(v1[c]), acc[c]);
    }
  }
  // cross-stream reduction: streams differ in lane bits 3..5
#pragma unroll
  for (int c = 0; c < 8; ++c) {
    float v = acc[c];
    v += __shfl_xor(v, 8, 64);
    v += __shfl_xor(v, 16, 64);
    v += __shfl_xor(v, 32, 64);
    acc[c] = v;
  }
  if (lane < 8) {
    size_t oi = ((size_t)wid << 6) + (size_t)lane * 8;
    float r[8];
    if (TprevF) {
      const float4* tp = (const float4*)(TprevF + oi);
      float4 t0 = tp[0], t1 = tp[1];
      r[0] = 2.f * acc[0] - t0.x; r[1] = 2.f * acc[1] - t0.y;
      r[2] = 2.f * acc[2] - t0.z; r[3] = 2.f * acc[3] - t0.w;
      r[4] = 2.f * acc[4] - t1.x; r[5] = 2.f * acc[5] - t1.y;
      r[6] = 2.f * acc[6] - t1.z; r[7] = 2.f * acc[7] - t1.w;
    } else if (TprevB) {
      u16x8 tp = *(const u16x8*)(TprevB + oi);
#pragma unroll
      for (int c = 0; c < 8; ++c) r[c] = 2.f * acc[c] - bf2f(tp[c]);
    } else {
#pragma unroll
      for (int c = 0; c < 8; ++c) r[c] = acc[c];
    }
    u16x8 o;
#pragma unroll
    for (int c = 0; c < 8; ++c) o[c] = f2bf(r[c]);
    *(u16x8*)(out_bf + oi) = o;
  }
}

// ---------------- weight repack: fp32 W[term][k][n] -> bf16 B-fragments ----------------
// frag fid = (term*2 + ks)*CT + ct ; lane holds B[k][n] with
// n = ct*16 + (lane&15), k = ks*32 + (lane>>4)*8 + e   (e = 0..7)

__global__ void repack_k(const float* __restrict__ W, ushortT* __restrict__ Bp, int H) {
  int t = blockIdx.x * 256 + threadIdx.x;
  int lane = t & 63, fid = t >> 6;
  int CT = H / 16;
  int nf = KT * 2 * CT;
  if (fid >= nf) return;
  int ct = fid % CT;
  int ks = (fid / CT) & 1;
  int term = fid / (CT * 2);
  int nn = ct * 16 + (lane & 15);
  int kb = ks * 32 + (lane >> 4) * 8;
  short8v out;
#pragma unroll
  for (int e = 0; e < 8; ++e)
    out[e] = (short)f2bf(W[((size_t)term * F + kb + e) * H + nn]);
  ((short8v*)Bp)[(size_t)fid * 64 + lane] = out;
}

// ------- MFMA fused-K: Y[n,H] = relu( sum_k Tk[n,64] @ W[k,64,H] + b ) -------
// block = 256 = 4 waves; each wave owns 16 rows x H cols. No LDS. bf16 in/out.

template <int H>
__global__ __launch_bounds__(256) void gemm5_mfma(const ushortT* __restrict__ T0,
                                                  const ushortT* __restrict__ T1,
                                                  const ushortT* __restrict__ T2,
                                                  const ushortT* __restrict__ T3,
                                                  const ushortT* __restrict__ T4,
                                                  const ushortT* __restrict__ Bp,
                                                  const float* __restrict__ bias,
                                                  ushortT* __restrict__ Y, int n) {
  constexpr int CT = H / 16;
  int wave = threadIdx.x >> 6;
  int lane = threadIdx.x & 63;
  int rbase = blockIdx.x * 64 + wave * 16;
  int arow = rbase + (lane & 15);
  if (arow > n - 1) arow = n - 1;  // clamp loads; stores guarded
  const short8v* bp = (const short8v*)Bp;
  const ushortT* Ts[5] = {T0, T1, T2, T3, T4};

  f32x4 acc[CT];
#pragma unroll
  for (int c = 0; c < CT; ++c) acc[c] = (f32x4){0.f, 0.f, 0.f, 0.f};

#pragma unroll
  for (int term = 0; term < KT; ++term) {
    const ushortT* T = Ts[term];
#pragma unroll
    for (int ks = 0; ks < 2; ++ks) {
      int kb = ks * 32 + (lane >> 4) * 8;
      short8v af = *(const short8v*)(T + (size_t)arow * F + kb);
      int fid0 = (term * 2 + ks) * CT;
#pragma unroll
      for (int ct = 0; ct < CT; ++ct) {
        short8v bf = bp[(size_t)(fid0 + ct) * 64 + lane];
        acc[ct] = __builtin_amdgcn_mfma_f32_16x16x32_bf16(af, bf, acc[ct], 0, 0, 0);
      }
    }
  }
  // C/D: col = lane&15, row = (lane>>4)*4 + reg
  int col0 = lane & 15;
  int rrow = rbase + (lane >> 4) * 4;
#pragma unroll
  for (int ct = 0; ct < CT; ++ct) {
    int col = ct * 16 + col0;
    float bv = bias[col];
#pragma unroll
    for (int i = 0; i < 4; ++i) {
      int gr = rrow + i;
      if (gr < n) Y[(size_t)gr * H + col] = f2bf(fmaxf(acc[ct][i] + bv, 0.f));
    }
  }
}

// ---------------- pooling + head (batch is sorted: contiguous ranges) ----------------

__global__ void gbounds_k(const int* __restrict__ batch, int* __restrict__ gstart, int n) {
  int g = threadIdx.x;
  if (g > GG) return;
  int lo = 0, hi = n;
  while (lo < hi) {
    int mid = (lo + hi) >> 1;
    if (batch[mid] < g) lo = mid + 1; else hi = mid;
  }
  gstart[g] = lo;
}

// stage 1: 64*PP blocks; block (g,p) sums its slice of graph g -> partials
__global__ __launch_bounds__(256) void pool1_k(const ushortT* __restrict__ h,
                                               const int* __restrict__ gstart,
                                               float* __restrict__ partials) {
  int g = blockIdx.x / PP, p = blockIdx.x % PP;
  int s = gstart[g], e = gstart[g + 1];
  int len = e - s;
  int ss = s + (int)((long long)len * p / PP);
  int se = s + (int)((long long)len * (p + 1) / PP);
  int tid = threadIdx.x;
  int c = tid & (H2C - 1), half = tid >> 7;
  float acc = 0.f;
  for (int i = ss + half; i < se; i += 2)
    acc += bf2f(h[(size_t)i * H2C + c]);
  __shared__ float sums[2][H2C];
  sums[half][c] = acc;
  __syncthreads();
  if (tid < H2C)
    partials[(size_t)blockIdx.x * H2C + tid] = sums[0][tid] + sums[1][tid];
}

// stage 2: 64 blocks x 128 threads; reduce partials, write hg + logits
__global__ __launch_bounds__(128) void pool2_k(const float* __restrict__ partials,
                                               const int* __restrict__ gstart,
                                               const float* __restrict__ Wl,
                                               const float* __restrict__ bl,
                                               float* __restrict__ outp) {
  int g = blockIdx.x, tid = threadIdx.x;  // tid = channel
  float s = 0.f;
  for (int p = 0; p < PP; ++p) s += partials[(size_t)(g * PP + p) * H2C + tid];
  float cntv = fmaxf((float)(gstart[g + 1] - gstart[g]), 1.f);
  float hg = s / cntv;
  outp[GG * CC + g * H2C + tid] = hg;
  __shared__ float red[2][H2C];
  red[0][tid] = hg * Wl[tid * CC + 0];
  red[1][tid] = hg * Wl[tid * CC + 1];
  __syncthreads();
  for (int st = 64; st > 0; st >>= 1) {
    if (tid < st) { red[0][tid] += red[0][tid + st]; red[1][tid] += red[1][tid + st]; }
    __syncthreads();
  }
  if (tid == 0) {
    outp[g * CC + 0] = red[0][0] + bl[0];
    outp[g * CC + 1] = red[1][0] + bl[1];
  }
}

// ---------------- driver ----------------

extern "C" void kernel_launch(void* const* d_in, const int* in_sizes, int n_in,
                              void* d_out, int out_size, void* d_ws, size_t ws_size,
                              hipStream_t stream) {
  const float* x    = (const float*)d_in[0];
  const int*   ei   = (const int*)d_in[1];
  const float* attr = (const float*)d_in[2];
  const int*   batch= (const int*)d_in[3];
  const float* W1 = (const float*)d_in[4];
  const float* b1 = (const float*)d_in[5];
  const float* W2 = (const float*)d_in[6];
  const float* b2 = (const float*)d_in[7];
  const float* W3 = (const float*)d_in[8];
  const float* b3 = (const float*)d_in[9];
  const float* Wl = (const float*)d_in[10];
  const float* bl = (const float*)d_in[11];
  float* outp = (float*)d_out;

  const int N = in_sizes[3];
  const int E = in_sizes[2];

  char* p = (char*)d_ws;
  auto alloc = [&](size_t bytes) {
    char* r = p;
    p += (bytes + 255) & ~(size_t)255;
    return r;
  };
  float* deg   = (float*)alloc((size_t)N * 4);
  int*   cnt   = (int*)alloc((size_t)N * 4);
  float* dis   = (float*)alloc((size_t)N * 4);
  int*   off   = (int*)alloc((size_t)(N + 1) * 4);
  ushortT* rankr = (ushortT*)alloc((size_t)E * 2);
  unsigned* ep4 = (unsigned*)alloc((size_t)E * 4);
  int*   bsum  = (int*)alloc(4096);
  int*   gstart= (int*)alloc((size_t)(GG + 1) * 4);
  ushortT* Bp1 = (ushortT*)alloc((size_t)KT * 2 * 4 * 64 * 8 * 2);
  ushortT* Bp2 = (ushortT*)alloc((size_t)KT * 2 * 4 * 64 * 8 * 2);
  ushortT* Bp3 = (ushortT*)alloc((size_t)KT * 2 * 8 * 64 * 8 * 2);
  // bf16 node matrices (N x 64)
  ushortT* X0  = (ushortT*)alloc((size_t)N * F * 2);
  ushortT* Abf = (ushortT*)alloc((size_t)N * F * 2);
  ushortT* Bbf = (ushortT*)alloc((size_t)N * F * 2);
  ushortT* Cbf = (ushortT*)alloc((size_t)N * F * 2);
  ushortT* Dbf = (ushortT*)alloc((size_t)N * F * 2);
  ushortT* Y1  = (ushortT*)alloc((size_t)N * F * 2);
  ushortT* Y2  = (ushortT*)alloc((size_t)N * F * 2);
  ushortT* Y3  = (ushortT*)alloc((size_t)N * H2C * 2);
  float* partials = (float*)alloc((size_t)GG * PP * H2C * 4);

  hipMemsetAsync(deg, 0, (size_t)N * 4, stream);
  hipMemsetAsync(cnt, 0, (size_t)N * 4, stream);

  int eb = (E + 255) / 256;
  int nb = (N + 255) / 256;
  int sb = (N + 1023) / 1024;

  // weight repacks + x conversion (independent of graph preprocessing)
  repack_k<<<(KT * 2 * 4 * 64 + 255) / 256, 256, 0, stream>>>(W1, Bp1, 64);
  repack_k<<<(KT * 2 * 4 * 64 + 255) / 256, 256, 0, stream>>>(W2, Bp2, 64);
  repack_k<<<(KT * 2 * 8 * 64 + 255) / 256, 256, 0, stream>>>(W3, Bp3, 128);
  cvt_k<<<((N * F / 4) + 255) / 256, 256, 0, stream>>>(x, X0, N * F / 4);

  pre_hist<<<eb, 256, 0, stream>>>(ei, attr, deg, cnt, rankr, E);
  dis_k<<<nb, 256, 0, stream>>>(deg, dis, N);
  scan_a<<<sb, 256, 0, stream>>>(cnt, bsum, N);
  scan_b<<<1, 64, 0, stream>>>(bsum, sb);
  scan_c<<<sb, 256, 0, stream>>>(cnt, bsum, off, N);
  scatter_k<<<eb, 256, 0, stream>>>(ei, attr, dis, rankr, off, ep4, E);
  gbounds_k<<<1, 128, 0, stream>>>(batch, gstart, N);

  int pb = (N + 3) / 4;
  auto prop = [&](const ushortT* z, const float* TprevF, const ushortT* TprevB,
                  ushortT* obf) {
    prop_k<<<pb, 256, 0, stream>>>(z, off, ep4, TprevF, TprevB, obf, N);
  };

  // layer: T0 bf16 (+ optional fp32 T0f for layer-1 where x is fp32)
  auto run_layer = [&](const ushortT* T0, const float* T0f, const ushortT* Bpk,
                       const float* bk, ushortT* Yout, int Hout) {
    prop(T0, nullptr, nullptr, Abf);              // T1 = L T0
    prop(Abf, T0f, T0f ? nullptr : T0, Bbf);      // T2 = 2L T1 - T0
    prop(Bbf, nullptr, Abf, Cbf);                 // T3 = 2L T2 - T1
    prop(Cbf, nullptr, Bbf, Dbf);                 // T4 = 2L T3 - T2
    if (Hout == 64)
      gemm5_mfma<64><<<(N + 63) / 64, 256, 0, stream>>>(T0, Abf, Bbf, Cbf, Dbf,
                                                        Bpk, bk, Yout, N);
    else
      gemm5_mfma<128><<<(N + 63) / 64, 256, 0, stream>>>(T0, Abf, Bbf, Cbf, Dbf,
                                                         Bpk, bk, Yout, N);
  };

  run_layer(X0, x,       Bp1, b1, Y1, 64);
  run_layer(Y1, nullptr, Bp2, b2, Y2, 64);
  run_layer(Y2, nullptr, Bp3, b3, Y3, 128);

  pool1_k<<<GG * PP, 256, 0, stream>>>(Y3, gstart, partials);
  pool2_k<<<GG, 128, 0, stream>>>(partials, gstart, Wl, bl, outp);
}